// Round 1
// baseline (324.024 us; speedup 1.0000x reference)
//
#include <hip/hip_runtime.h>

// Problem constants (from reference)
#define KA 240000
#define NI 4
#define MG 50
#define NSEL 256u
#define CAPL 4096          // boundary-bin member cap per group (expect ~260)
#define BPI 235            // blocks per image: 235*256*4 = 240640 >= 240000
#define GRID (BPI * NI)    // 940 blocks

typedef unsigned int u32;

// ws layout (u32 units):
//   hist 8x2048 @0 | meta[32] @16384 (us[0..8)|R[8..16)|done[16..24)|cnt[24..32))
//   | arr1[4] @16416 | arr2[4] @16420 | list @16424 (8*CAPL*2) | flags after
#define METAO 16384
#define ARR1O 16416
#define ARR2O 16420
#define LISTO 16424
#define ZERON 16424        // words zeroed each iteration
#define ONE_F 0x3F800000u  // 1.0f bits

// monotone f32 -> u32 sortkey (order-preserving for all finite floats)
static __device__ __forceinline__ u32 sortkey32(float f) {
    u32 b = __float_as_uint(f);
    return (b & 0x80000000u) ? ~b : (b | 0x80000000u);
}
// agent-scope atomic dword store: bypasses per-XCD L2, so scattered 1.0 patches
// from blocks on different XCDs can share a 64B line without lost updates.
static __device__ __forceinline__ void patch1(u32* p) {
    __hip_atomic_store(p, ONE_F, __ATOMIC_RELAXED, __HIP_MEMORY_SCOPE_AGENT);
}
// agent-scope atomic load: coherent read of data written by other blocks
// (device-scope atomicAdd RMWs / agent stores) within the same kernel.
static __device__ __forceinline__ u32 aload(const u32* p) {
    return __hip_atomic_load(p, __ATOMIC_RELAXED, __HIP_MEMORY_SCOPE_AGENT);
}

// ---------------- K1: fused zero + IoU/argmax + targets + weight-prewrite + hist
//                  + last-block-per-image boundary scan ----------------
extern "C" __global__ void __launch_bounds__(256, 4)
AnchorTargetLayer_48052094107725_kernel(
    const float4* __restrict__ anchors, const float* __restrict__ scores,
    const float4* __restrict__ gtb, const int* __restrict__ glab,
    float* __restrict__ out, u32* __restrict__ flags, u32* __restrict__ ws) {
#pragma clang fp contract(off)
    __shared__ float4 gA[MG];
    __shared__ int glb[MG];
    __shared__ u32 lh[2048];        // packed hist: pos low16 | neg high16
    const int bx = blockIdx.x;
    const int tid = threadIdx.x;
    const int n = bx / BPI;
    const int kb = bx - n * BPI;

    if (tid < 18) {
        const int i = bx * 18 + tid;      // 940*18 = 16920 >= 16424
        if (i < ZERON) atomicExch(&ws[i], 0u);   // coherent with later atomic merges
    }
    for (int i = tid; i < 2048; i += 256) lh[i] = 0;
    if (tid < MG) {
        gA[tid] = gtb[n * MG + tid];
        glb[tid] = glab[n * MG + tid];
    }
    __syncthreads();

    const int k0 = (kb * 256 + tid) * 4;   // 4 consecutive anchors (KA%4==0)
    if (k0 < KA) {
        float ax0[4], ay0[4], ax2[4], ay2[4];
        #pragma unroll
        for (int j = 0; j < 4; ++j) {
            const float4 A = anchors[k0 + j];
            ax0[j] = A.x; ay0[j] = A.y; ax2[j] = A.z; ay2[j] = A.w;
        }
        float aaw[4], aah[4], aar[4], bst[4];
        int bix[4];
        #pragma unroll
        for (int j = 0; j < 4; ++j) {
            aaw[j] = ax2[j] - ax0[j];
            aah[j] = ay2[j] - ay0[j];
            aar[j] = aaw[j] * aah[j];
            bst[j] = -1.0f;
            bix[j] = 0;
        }
        for (int m = 0; m < MG; m += 2) {
            const float4 Ga = gA[m];
            const float4 Gb = gA[m + 1];
            const float gaA = (Ga.z - Ga.x) * (Ga.w - Ga.y);   // same ops as reference
            const float gaB = (Gb.z - Gb.x) * (Gb.w - Gb.y);
            #pragma unroll
            for (int j = 0; j < 4; ++j) {
                const float wa = fmaxf(fminf(ax2[j], Ga.z) - fmaxf(ax0[j], Ga.x), 0.0f);
                const float ha = fmaxf(fminf(ay2[j], Ga.w) - fmaxf(ay0[j], Ga.y), 0.0f);
                const float ia = wa * ha;
                const float qa = ia / (((aar[j] + gaA) - ia) + 1e-8f);  // IEEE f32 div
                const float wb = fmaxf(fminf(ax2[j], Gb.z) - fmaxf(ax0[j], Gb.x), 0.0f);
                const float hb = fmaxf(fminf(ay2[j], Gb.w) - fmaxf(ay0[j], Gb.y), 0.0f);
                const float ib = wb * hb;
                const float qb = ib / (((aar[j] + gaB) - ib) + 1e-8f);
                if (qa > bst[j]) { bst[j] = qa; bix[j] = m; }       // strict >: first idx
                if (qb > bst[j]) { bst[j] = qb; bix[j] = m + 1; }
            }
        }

        const int nk = n * KA + k0;
        const float4 s4 = ((const float4*)scores)[nk >> 2];
        const float scv[4] = {s4.x, s4.y, s4.z, s4.w};

        float clsv[4];
        float4 regv[4];
        u32 flagpack = 0;
        #pragma unroll
        for (int j = 0; j < 4; ++j) {
            const bool pos = bst[j] >= 0.7f;
            const bool neg = bst[j] < 0.3f;
            clsv[j] = pos ? (float)glb[bix[j]] : 0.0f;
            float4 rv = make_float4(0.0f, 0.0f, 0.0f, 0.0f);
            if (pos) {
                const float4 Gm = gA[bix[j]];
                const float gw = Gm.z - Gm.x, gh = Gm.w - Gm.y;
                const float gcx = Gm.x + 0.5f * gw, gcy = Gm.y + 0.5f * gh;
                const float acx = ax0[j] + 0.5f * aaw[j], acy = ay0[j] + 0.5f * aah[j];
                rv.x = (gcx - acx) / aaw[j];
                rv.y = (gcy - acy) / aah[j];
                rv.z = logf(gw / aaw[j]);
                rv.w = logf(gh / aah[j]);
            }
            regv[j] = rv;
            const u32 fl = pos ? 1u : (neg ? 2u : 0u);
            flagpack |= fl << (8 * j);
            if (fl) atomicAdd(&lh[sortkey32(scv[j]) >> 21], fl == 2u ? 0x10000u : 1u);
        }
        const size_t NK = (size_t)NI * KA;
        const size_t NK4 = NK / 4;
        const int t4 = nk >> 2;
        ((float4*)out)[t4] = make_float4(clsv[0], clsv[1], clsv[2], clsv[3]);
        float4* regp = ((float4*)(out + NK)) + nk;
        regp[0] = regv[0]; regp[1] = regv[1]; regp[2] = regv[2]; regp[3] = regv[3];
        const float4 z4 = make_float4(0.0f, 0.0f, 0.0f, 0.0f);
        ((float4*)out)[5 * NK4 + t4] = z4;   // cls_weights prewrite
        ((float4*)out)[6 * NK4 + t4] = z4;   // reg_weights prewrite
        flags[t4] = flagpack;
    }
    __syncthreads();
    // merge packed LDS histogram into per-group global hist
    const int gp = 2 * n;
    for (int i = tid; i < 2048; i += 256) {
        const u32 c = lh[i];
        if (c & 0xFFFFu) atomicAdd(&ws[gp * 2048 + i], c & 0xFFFFu);
        if (c >> 16)     atomicAdd(&ws[(gp + 1) * 2048 + i], c >> 16);
    }

    // ---- ticket: last block of image n computes the boundary for its 2 groups ----
    __threadfence();                 // release this block's hist RMWs (agent scope)
    __syncthreads();
    __shared__ u32 s_last;
    if (tid == 0)
        s_last = __hip_atomic_fetch_add(&ws[ARR1O + n], 1u,
                                        __ATOMIC_ACQ_REL, __HIP_MEMORY_SCOPE_AGENT);
    __syncthreads();
    if (s_last == BPI - 1) {
        // hist for groups 2n/2n+1 is complete. Scan once (was 940x redundant in kP).
        for (int gi = 0; gi < 2; ++gi) {
            const int g = 2 * n + gi;
            u32 loc[8];
            u32 s = 0;
            const int base = g * 2048 + tid * 8;
            #pragma unroll
            for (int j = 0; j < 8; ++j) { loc[j] = aload(&ws[base + j]); s += loc[j]; }
            lh[tid] = s;                       // reuse lh[0..255] as scan scratch
            __syncthreads();
            for (int d = 1; d < 256; d <<= 1) {
                const u32 add = (tid + d < 256) ? lh[tid + d] : 0u;
                __syncthreads();
                lh[tid] += add;
                __syncthreads();
            }
            if (tid == 0)
                ws[METAO + 16 + g] = (lh[0] < NSEL) ? 1u : 0u;   // done (take-all)
            u32 run = (tid < 255) ? lh[tid + 1] : 0u;
            #pragma unroll
            for (int j = 7; j >= 0; --j) {
                const u32 Sj = run + loc[j];
                if (Sj >= NSEL && run < NSEL) {        // exactly one thread matches
                    ws[METAO + g] = (u32)(tid * 8 + j);   // boundary 11-bit prefix
                    ws[METAO + 8 + g] = NSEL - run;       // slots within boundary bin
                }
                run = Sj;
            }
            __syncthreads();
        }
    }
}

// ---------------- K2: sparse weight patches + tie collection (scan-free)
//                  + last-block-per-image boundary-bin refinement ----------------
__global__ void __launch_bounds__(256) kP(const float* __restrict__ scores,
                                          const u32* __restrict__ flagsW,
                                          u32* __restrict__ ws,
                                          float* __restrict__ out) {
    __shared__ u32 s_us[2], s_done[2];
    const int bx = blockIdx.x, tid = threadIdx.x;
    const int n = bx / BPI, kb = bx - n * BPI;
    u32* meta = ws + METAO;
    u32* list = ws + LISTO;

    if (tid < 2) {                   // boundary meta written once by K1's last block
        s_us[tid]   = meta[2 * n + tid];
        s_done[tid] = meta[16 + 2 * n + tid];
    }
    __syncthreads();

    const size_t NK = (size_t)NI * KA;
    u32* o32 = (u32*)out;

    const int k0 = (kb * 256 + tid) * 4;
    if (k0 < KA) {                   // guard (no return: all threads reach ticket2)
        const int nk = n * KA + k0;
        const u32 fw = flagsW[nk >> 2];
        if (fw) {                    // some member among these 4 anchors
            const float4 s4 = ((const float4*)scores)[nk >> 2];
            const float scv[4] = {s4.x, s4.y, s4.z, s4.w};
            #pragma unroll
            for (int j = 0; j < 4; ++j) {
                const u32 f = (fw >> (8 * j)) & 255u;
                if (!f) continue;
                const int gi = (f == 2u) ? 1 : 0;
                bool in = false;
                if (s_done[gi]) {
                    in = true;                       // group < 256 members: take all
                } else {
                    const u32 key = sortkey32(scv[j]);
                    const u32 p11 = key >> 21;
                    if (p11 > s_us[gi]) {
                        in = true;
                    } else if (p11 == s_us[gi]) {
                        // boundary-bin member: defer verdict (weight stays 0)
                        const int g = 2 * n + gi;
                        const u32 p = atomicAdd(&meta[24 + g], 1u);
                        if (p < CAPL) {
                            list[(g * CAPL + p) * 2] = key;
                            list[(g * CAPL + p) * 2 + 1] = (u32)(k0 + j);
                        }
                    }
                }
                if (in) {
                    patch1(&o32[5 * NK + nk + j]);              // cls_weights = 1.0
                    if (f == 1u) patch1(&o32[6 * NK + nk + j]); // reg_weights = 1.0
                }
            }
        }
    }

    // ---- ticket2: last block of image n refines boundary bins of its 2 groups ----
    __threadfence();                 // release this block's list stores
    __syncthreads();
    __shared__ u32 s_last;
    if (tid == 0)
        s_last = __hip_atomic_fetch_add(&ws[ARR2O + n], 1u,
                                        __ATOMIC_ACQ_REL, __HIP_MEMORY_SCOPE_AGENT);
    __syncthreads();
    if (s_last != BPI - 1) return;   // uniform exit for non-last blocks

    __shared__ u32 h2[1024];
    __shared__ u32 cs[256];
    __shared__ u32 s_usb, s_R2, s_tc;
    __shared__ u32 tk[256], ti[256];
    for (int gi = 0; gi < 2; ++gi) {
        if (s_done[gi]) continue;    // take-all group (block-uniform skip)
        const int g = 2 * n + gi;
        u32 c = aload(&meta[24 + g]);
        if (c > CAPL) c = CAPL;
        const u32 R1 = meta[8 + g];  // written by K1 (cross-kernel visible)
        for (u32 i = tid; i < 1024; i += 256) h2[i] = 0;
        if (tid == 0) s_tc = 0;
        __syncthreads();
        for (u32 j = tid; j < c; j += 256)
            atomicAdd(&h2[(aload(&list[(g * CAPL + j) * 2]) >> 11) & 1023u], 1u);
        __syncthreads();
        // suffix scan over 1024 sub-bins
        u32 loc[4];
        u32 s = 0;
        #pragma unroll
        for (int j = 0; j < 4; ++j) { loc[j] = h2[tid * 4 + j]; s += loc[j]; }
        cs[tid] = s;
        __syncthreads();
        for (int d = 1; d < 256; d <<= 1) {
            const u32 add = (tid + d < 256) ? cs[tid + d] : 0u;
            __syncthreads();
            cs[tid] += add;
            __syncthreads();
        }
        u32 run = (tid < 255) ? cs[tid + 1] : 0u;
        #pragma unroll
        for (int j = 3; j >= 0; --j) {
            const u32 Sj = run + loc[j];
            if (Sj >= R1 && run < R1) { s_usb = (u32)(tid * 4 + j); s_R2 = R1 - run; }
            run = Sj;
        }
        __syncthreads();
        const u32 usb = s_usb, R2 = s_R2;
        const bool posg = (gi == 0);
        for (u32 j = tid; j < c; j += 256) {
            const u32 key = aload(&list[(g * CAPL + j) * 2]);
            const u32 idx = aload(&list[(g * CAPL + j) * 2 + 1]);
            const u32 sb = (key >> 11) & 1023u;
            if (sb > usb) {
                const size_t o = (size_t)n * KA + idx;
                patch1(&o32[5 * NK + o]);
                if (posg) patch1(&o32[6 * NK + o]);
            } else if (sb == usb) {
                const u32 p = atomicAdd(&s_tc, 1u);
                if (p < 256) { tk[p] = key; ti[p] = idx; }
            }
        }
        __syncthreads();
        u32 tc = s_tc;
        if (tc > 256) tc = 256;
        // rank tiny tie set by (key desc, idx asc) — stable top_k semantics
        for (u32 i = tid; i < tc; i += 256) {
            const u32 ki = tk[i], ii = ti[i];
            u32 rank = 0;
            for (u32 j2 = 0; j2 < tc; ++j2) {
                const u32 kj = tk[j2];
                if (kj > ki || (kj == ki && ti[j2] < ii)) rank++;
            }
            if (rank < R2) {
                const size_t o = (size_t)n * KA + ii;
                patch1(&o32[5 * NK + o]);
                if (posg) patch1(&o32[6 * NK + o]);
            }
        }
        __syncthreads();             // before next gi reuses h2/cs/s_tc
    }
}

extern "C" void kernel_launch(void* const* d_in, const int* in_sizes, int n_in,
                              void* d_out, int out_size, void* d_ws, size_t ws_size,
                              hipStream_t stream) {
    (void)in_sizes; (void)n_in; (void)out_size; (void)ws_size;
    const float4* anchors = (const float4*)d_in[0];   // (K,4) f32
    const float*  scores  = (const float*)d_in[1];    // (N,K) f32
    const float4* gtb     = (const float4*)d_in[2];   // (N,M,4) f32
    const int*    glab    = (const int*)d_in[3];      // (N,M) int32
    float* out = (float*)d_out;

    u32* ws = (u32*)d_ws;
    u32* flags = ws + LISTO + 8 * CAPL * 2;           // u32 per 4 anchors

    AnchorTargetLayer_48052094107725_kernel<<<GRID, 256, 0, stream>>>(
        anchors, scores, gtb, glab, out, flags, ws);
    kP<<<GRID, 256, 0, stream>>>(scores, flags, ws, out);
}

// Round 2
// 144.511 us; speedup vs baseline: 2.2422x; 2.2422x over previous
//
#include <hip/hip_runtime.h>

// Problem constants (from reference)
#define KA 240000
#define NI 4
#define MG 50
#define NSEL 256u
#define CAPL 4096          // boundary-bin member cap per group (expect ~260)
#define BPI 235            // blocks per image: 235*256*4 = 240640 >= 240000
#define GRID (BPI * NI)    // 940 blocks

typedef unsigned int u32;

// ws layout (u32 units):
//   hist 8x2048 @0 | meta[32] @16384 (us[0..8)|R[8..16)|done[16..24)|cnt[24..32))
//   | arr1[4] @16416 | arr2[4] @16420 | list @16424 (8*CAPL*2) | flags after
// ws[0..ZERON) is zeroed by hipMemsetAsync before K1 (race-free, stream-ordered).
#define METAO 16384
#define ARR1O 16416
#define ARR2O 16420
#define LISTO 16424
#define ZERON 16424        // words zeroed each iteration
#define ONE_F 0x3F800000u  // 1.0f bits

// monotone f32 -> u32 sortkey (order-preserving for all finite floats)
static __device__ __forceinline__ u32 sortkey32(float f) {
    u32 b = __float_as_uint(f);
    return (b & 0x80000000u) ? ~b : (b | 0x80000000u);
}
// agent-scope RELAXED atomic store: executes at the coherence point (bypasses
// per-XCD L2) with NO cache-maintenance instructions.
static __device__ __forceinline__ void patch1(u32* p) {
    __hip_atomic_store(p, ONE_F, __ATOMIC_RELAXED, __HIP_MEMORY_SCOPE_AGENT);
}
static __device__ __forceinline__ void astore(u32* p, u32 v) {
    __hip_atomic_store(p, v, __ATOMIC_RELAXED, __HIP_MEMORY_SCOPE_AGENT);
}
// agent-scope RELAXED atomic load: reads the coherence point.
static __device__ __forceinline__ u32 aload(const u32* p) {
    return __hip_atomic_load(p, __ATOMIC_RELAXED, __HIP_MEMORY_SCOPE_AGENT);
}
// Drain this wave's outstanding VMEM ops (atomics included) WITHOUT any L2
// writeback/invalidate. Prior atomics have reached the coherence point when
// this returns — the cheap release half of the arrival ticket.
static __device__ __forceinline__ void drain_vmem() {
    asm volatile("s_waitcnt vmcnt(0)" ::: "memory");
}

// ---------------- K1: fused IoU/argmax + targets + weight-prewrite + hist
//                  + last-block-per-image boundary scan (relaxed ticket) ----------------
extern "C" __global__ void __launch_bounds__(256, 4)
AnchorTargetLayer_48052094107725_kernel(
    const float4* __restrict__ anchors, const float* __restrict__ scores,
    const float4* __restrict__ gtb, const int* __restrict__ glab,
    float* __restrict__ out, u32* __restrict__ flags, u32* __restrict__ ws) {
#pragma clang fp contract(off)
    __shared__ float4 gA[MG];
    __shared__ int glb[MG];
    __shared__ u32 lh[2048];        // packed hist: pos low16 | neg high16
    const int bx = blockIdx.x;
    const int tid = threadIdx.x;
    const int n = bx / BPI;
    const int kb = bx - n * BPI;

    for (int i = tid; i < 2048; i += 256) lh[i] = 0;
    if (tid < MG) {
        gA[tid] = gtb[n * MG + tid];
        glb[tid] = glab[n * MG + tid];
    }
    __syncthreads();

    const int k0 = (kb * 256 + tid) * 4;   // 4 consecutive anchors (KA%4==0)
    if (k0 < KA) {
        float ax0[4], ay0[4], ax2[4], ay2[4];
        #pragma unroll
        for (int j = 0; j < 4; ++j) {
            const float4 A = anchors[k0 + j];
            ax0[j] = A.x; ay0[j] = A.y; ax2[j] = A.z; ay2[j] = A.w;
        }
        float aaw[4], aah[4], aar[4], bst[4];
        int bix[4];
        #pragma unroll
        for (int j = 0; j < 4; ++j) {
            aaw[j] = ax2[j] - ax0[j];
            aah[j] = ay2[j] - ay0[j];
            aar[j] = aaw[j] * aah[j];
            bst[j] = -1.0f;
            bix[j] = 0;
        }
        for (int m = 0; m < MG; m += 2) {
            const float4 Ga = gA[m];
            const float4 Gb = gA[m + 1];
            const float gaA = (Ga.z - Ga.x) * (Ga.w - Ga.y);   // same ops as reference
            const float gaB = (Gb.z - Gb.x) * (Gb.w - Gb.y);
            #pragma unroll
            for (int j = 0; j < 4; ++j) {
                const float wa = fmaxf(fminf(ax2[j], Ga.z) - fmaxf(ax0[j], Ga.x), 0.0f);
                const float ha = fmaxf(fminf(ay2[j], Ga.w) - fmaxf(ay0[j], Ga.y), 0.0f);
                const float ia = wa * ha;
                const float qa = ia / (((aar[j] + gaA) - ia) + 1e-8f);  // IEEE f32 div
                const float wb = fmaxf(fminf(ax2[j], Gb.z) - fmaxf(ax0[j], Gb.x), 0.0f);
                const float hb = fmaxf(fminf(ay2[j], Gb.w) - fmaxf(ay0[j], Gb.y), 0.0f);
                const float ib = wb * hb;
                const float qb = ib / (((aar[j] + gaB) - ib) + 1e-8f);
                if (qa > bst[j]) { bst[j] = qa; bix[j] = m; }       // strict >: first idx
                if (qb > bst[j]) { bst[j] = qb; bix[j] = m + 1; }
            }
        }

        const int nk = n * KA + k0;
        const float4 s4 = ((const float4*)scores)[nk >> 2];
        const float scv[4] = {s4.x, s4.y, s4.z, s4.w};

        float clsv[4];
        float4 regv[4];
        u32 flagpack = 0;
        #pragma unroll
        for (int j = 0; j < 4; ++j) {
            const bool pos = bst[j] >= 0.7f;
            const bool neg = bst[j] < 0.3f;
            clsv[j] = pos ? (float)glb[bix[j]] : 0.0f;
            float4 rv = make_float4(0.0f, 0.0f, 0.0f, 0.0f);
            if (pos) {
                const float4 Gm = gA[bix[j]];
                const float gw = Gm.z - Gm.x, gh = Gm.w - Gm.y;
                const float gcx = Gm.x + 0.5f * gw, gcy = Gm.y + 0.5f * gh;
                const float acx = ax0[j] + 0.5f * aaw[j], acy = ay0[j] + 0.5f * aah[j];
                rv.x = (gcx - acx) / aaw[j];
                rv.y = (gcy - acy) / aah[j];
                rv.z = logf(gw / aaw[j]);
                rv.w = logf(gh / aah[j]);
            }
            regv[j] = rv;
            const u32 fl = pos ? 1u : (neg ? 2u : 0u);
            flagpack |= fl << (8 * j);
            if (fl) atomicAdd(&lh[sortkey32(scv[j]) >> 21], fl == 2u ? 0x10000u : 1u);
        }
        const size_t NK = (size_t)NI * KA;
        const size_t NK4 = NK / 4;
        const int t4 = nk >> 2;
        ((float4*)out)[t4] = make_float4(clsv[0], clsv[1], clsv[2], clsv[3]);
        float4* regp = ((float4*)(out + NK)) + nk;
        regp[0] = regv[0]; regp[1] = regv[1]; regp[2] = regv[2]; regp[3] = regv[3];
        const float4 z4 = make_float4(0.0f, 0.0f, 0.0f, 0.0f);
        ((float4*)out)[5 * NK4 + t4] = z4;   // cls_weights prewrite
        ((float4*)out)[6 * NK4 + t4] = z4;   // reg_weights prewrite
        flags[t4] = flagpack;
    }
    __syncthreads();
    // merge packed LDS histogram into per-group global hist (device-scope atomics
    // execute at the coherence point — no fence needed for cross-block visibility)
    const int gp = 2 * n;
    for (int i = tid; i < 2048; i += 256) {
        const u32 c = lh[i];
        if (c & 0xFFFFu) atomicAdd(&ws[gp * 2048 + i], c & 0xFFFFu);
        if (c >> 16)     atomicAdd(&ws[(gp + 1) * 2048 + i], c >> 16);
    }

    // ---- relaxed ticket: last block of image n computes its 2 group boundaries ----
    drain_vmem();                    // every wave: hist adds reached coherence point
    __syncthreads();
    __shared__ u32 s_last;
    if (tid == 0)
        s_last = __hip_atomic_fetch_add(&ws[ARR1O + n], 1u,
                                        __ATOMIC_RELAXED, __HIP_MEMORY_SCOPE_AGENT);
    __syncthreads();
    if (s_last == BPI - 1) {
        // hist for groups 2n/2n+1 complete. Scan once (was 940x redundant in kP).
        for (int gi = 0; gi < 2; ++gi) {
            const int g = 2 * n + gi;
            u32 loc[8];
            u32 s = 0;
            const int base = g * 2048 + tid * 8;
            #pragma unroll
            for (int j = 0; j < 8; ++j) { loc[j] = aload(&ws[base + j]); s += loc[j]; }
            lh[tid] = s;                       // reuse lh[0..255] as scan scratch
            __syncthreads();
            for (int d = 1; d < 256; d <<= 1) {
                const u32 add = (tid + d < 256) ? lh[tid + d] : 0u;
                __syncthreads();
                lh[tid] += add;
                __syncthreads();
            }
            if (tid == 0)
                ws[METAO + 16 + g] = (lh[0] < NSEL) ? 1u : 0u;   // done (take-all)
            u32 run = (tid < 255) ? lh[tid + 1] : 0u;
            #pragma unroll
            for (int j = 7; j >= 0; --j) {
                const u32 Sj = run + loc[j];
                if (Sj >= NSEL && run < NSEL) {        // exactly one thread matches
                    ws[METAO + g] = (u32)(tid * 8 + j);   // boundary 11-bit prefix
                    ws[METAO + 8 + g] = NSEL - run;       // slots within boundary bin
                }
                run = Sj;
            }
            __syncthreads();
        }
    }
}

// ---------------- K2: sparse weight patches + tie collection (scan-free)
//                  + last-block-per-image boundary-bin refinement ----------------
__global__ void __launch_bounds__(256) kP(const float* __restrict__ scores,
                                          const u32* __restrict__ flagsW,
                                          u32* __restrict__ ws,
                                          float* __restrict__ out) {
    __shared__ u32 s_us[2], s_done[2];
    const int bx = blockIdx.x, tid = threadIdx.x;
    const int n = bx / BPI, kb = bx - n * BPI;
    u32* meta = ws + METAO;
    u32* list = ws + LISTO;

    if (tid < 2) {                   // boundary meta written once by K1's last block
        s_us[tid]   = meta[2 * n + tid];
        s_done[tid] = meta[16 + 2 * n + tid];
    }
    __syncthreads();

    const size_t NK = (size_t)NI * KA;
    u32* o32 = (u32*)out;

    const int k0 = (kb * 256 + tid) * 4;
    if (k0 < KA) {                   // guard (no return: all threads reach ticket2)
        const int nk = n * KA + k0;
        const u32 fw = flagsW[nk >> 2];
        if (fw) {                    // some member among these 4 anchors
            const float4 s4 = ((const float4*)scores)[nk >> 2];
            const float scv[4] = {s4.x, s4.y, s4.z, s4.w};
            #pragma unroll
            for (int j = 0; j < 4; ++j) {
                const u32 f = (fw >> (8 * j)) & 255u;
                if (!f) continue;
                const int gi = (f == 2u) ? 1 : 0;
                bool in = false;
                if (s_done[gi]) {
                    in = true;                       // group < 256 members: take all
                } else {
                    const u32 key = sortkey32(scv[j]);
                    const u32 p11 = key >> 21;
                    if (p11 > s_us[gi]) {
                        in = true;
                    } else if (p11 == s_us[gi]) {
                        // boundary-bin member: defer verdict (weight stays 0)
                        const int g = 2 * n + gi;
                        const u32 p = atomicAdd(&meta[24 + g], 1u);
                        if (p < CAPL) {
                            astore(&list[(g * CAPL + p) * 2], key);
                            astore(&list[(g * CAPL + p) * 2 + 1], (u32)(k0 + j));
                        }
                    }
                }
                if (in) {
                    patch1(&o32[5 * NK + nk + j]);              // cls_weights = 1.0
                    if (f == 1u) patch1(&o32[6 * NK + nk + j]); // reg_weights = 1.0
                }
            }
        }
    }

    // ---- relaxed ticket2: last block of image n refines its 2 groups ----
    drain_vmem();                    // list stores + cnt adds at coherence point
    __syncthreads();
    __shared__ u32 s_last;
    if (tid == 0)
        s_last = __hip_atomic_fetch_add(&ws[ARR2O + n], 1u,
                                        __ATOMIC_RELAXED, __HIP_MEMORY_SCOPE_AGENT);
    __syncthreads();
    if (s_last != BPI - 1) return;   // uniform exit for non-last blocks

    __shared__ u32 h2[1024];
    __shared__ u32 cs[256];
    __shared__ u32 s_usb, s_R2, s_tc;
    __shared__ u32 tk[256], ti[256];
    for (int gi = 0; gi < 2; ++gi) {
        if (s_done[gi]) continue;    // take-all group (block-uniform skip)
        const int g = 2 * n + gi;
        u32 c = aload(&meta[24 + g]);
        if (c > CAPL) c = CAPL;
        const u32 R1 = meta[8 + g];  // written by K1 (cross-kernel visible)
        for (u32 i = tid; i < 1024; i += 256) h2[i] = 0;
        if (tid == 0) s_tc = 0;
        __syncthreads();
        for (u32 j = tid; j < c; j += 256)
            atomicAdd(&h2[(aload(&list[(g * CAPL + j) * 2]) >> 11) & 1023u], 1u);
        __syncthreads();
        // suffix scan over 1024 sub-bins
        u32 loc[4];
        u32 s = 0;
        #pragma unroll
        for (int j = 0; j < 4; ++j) { loc[j] = h2[tid * 4 + j]; s += loc[j]; }
        cs[tid] = s;
        __syncthreads();
        for (int d = 1; d < 256; d <<= 1) {
            const u32 add = (tid + d < 256) ? cs[tid + d] : 0u;
            __syncthreads();
            cs[tid] += add;
            __syncthreads();
        }
        u32 run = (tid < 255) ? cs[tid + 1] : 0u;
        #pragma unroll
        for (int j = 3; j >= 0; --j) {
            const u32 Sj = run + loc[j];
            if (Sj >= R1 && run < R1) { s_usb = (u32)(tid * 4 + j); s_R2 = R1 - run; }
            run = Sj;
        }
        __syncthreads();
        const u32 usb = s_usb, R2 = s_R2;
        const bool posg = (gi == 0);
        for (u32 j = tid; j < c; j += 256) {
            const u32 key = aload(&list[(g * CAPL + j) * 2]);
            const u32 idx = aload(&list[(g * CAPL + j) * 2 + 1]);
            const u32 sb = (key >> 11) & 1023u;
            if (sb > usb) {
                const size_t o = (size_t)n * KA + idx;
                patch1(&o32[5 * NK + o]);
                if (posg) patch1(&o32[6 * NK + o]);
            } else if (sb == usb) {
                const u32 p = atomicAdd(&s_tc, 1u);
                if (p < 256) { tk[p] = key; ti[p] = idx; }
            }
        }
        __syncthreads();
        u32 tc = s_tc;
        if (tc > 256) tc = 256;
        // rank tiny tie set by (key desc, idx asc) — stable top_k semantics
        for (u32 i = tid; i < tc; i += 256) {
            const u32 ki = tk[i], ii = ti[i];
            u32 rank = 0;
            for (u32 j2 = 0; j2 < tc; ++j2) {
                const u32 kj = tk[j2];
                if (kj > ki || (kj == ki && ti[j2] < ii)) rank++;
            }
            if (rank < R2) {
                const size_t o = (size_t)n * KA + ii;
                patch1(&o32[5 * NK + o]);
                if (posg) patch1(&o32[6 * NK + o]);
            }
        }
        __syncthreads();             // before next gi reuses h2/cs/s_tc
    }
}

extern "C" void kernel_launch(void* const* d_in, const int* in_sizes, int n_in,
                              void* d_out, int out_size, void* d_ws, size_t ws_size,
                              hipStream_t stream) {
    (void)in_sizes; (void)n_in; (void)out_size; (void)ws_size;
    const float4* anchors = (const float4*)d_in[0];   // (K,4) f32
    const float*  scores  = (const float*)d_in[1];    // (N,K) f32
    const float4* gtb     = (const float4*)d_in[2];   // (N,M,4) f32
    const int*    glab    = (const int*)d_in[3];      // (N,M) int32
    float* out = (float*)d_out;

    u32* ws = (u32*)d_ws;
    u32* flags = ws + LISTO + 8 * CAPL * 2;           // u32 per 4 anchors

    // race-free reset of hist/meta/arrival counters (stream-ordered, capturable)
    hipMemsetAsync(ws, 0, (size_t)ZERON * sizeof(u32), stream);

    AnchorTargetLayer_48052094107725_kernel<<<GRID, 256, 0, stream>>>(
        anchors, scores, gtb, glab, out, flags, ws);
    kP<<<GRID, 256, 0, stream>>>(scores, flags, ws, out);
}

// Round 3
// 137.940 us; speedup vs baseline: 2.3490x; 1.0476x over previous
//
#include <hip/hip_runtime.h>

// Problem constants (from reference)
#define KA 240000
#define NI 4
#define MG 50
#define NSEL 256u
#define CAPL 4096          // boundary-bin member cap per group (expect ~260)
#define BPI 235            // kP blocks per image: 235*256*4 = 240640 >= 240000
#define GRID (BPI * NI)    // 940 blocks (kP)
#define BPIK 469           // K1 blocks per image: 469*256*2 = 240128 >= 240000
#define GRIDK (BPIK * NI)  // 1876 blocks (K1) -> ~7.3 blocks/CU, fills wave slots

typedef unsigned int u32;

// ws layout (u32 units): hist 8x2048 @0 | meta[32] @16384 | list @16416 (8*CAPL*2)
// meta: us[0..8) | R[8..16) | done[16..24) | cnt[24..32)
#define METAO 16384
#define LISTO (METAO + 32)
#define ONE_F 0x3F800000u   // 1.0f bits

// monotone f32 -> u32 sortkey (order-preserving for all finite floats)
static __device__ __forceinline__ u32 sortkey32(float f) {
    u32 b = __float_as_uint(f);
    return (b & 0x80000000u) ? ~b : (b | 0x80000000u);
}
// agent-scope atomic dword store: bypasses per-XCD L2, so scattered 1.0 patches
// from blocks on different XCDs can share a 64B line without lost updates.
static __device__ __forceinline__ void patch1(u32* p) {
    __hip_atomic_store(p, ONE_F, __ATOMIC_RELAXED, __HIP_MEMORY_SCOPE_AGENT);
}

// ---------------- D1: fused zero + IoU/argmax + targets + weight-prewrite + hist ----------------
// 2 anchors/thread (was 4): grid 1876 blocks fills ~92% of wave slots (was 46%,
// grid-limited at 940). Same per-anchor arithmetic and m-loop order as the
// verified 137.1us baseline. launch_bounds(256,8) pins VGPR<=64 for 8 blocks/CU.
extern "C" __global__ void __launch_bounds__(256, 8)
AnchorTargetLayer_48052094107725_kernel(
    const float4* __restrict__ anchors, const float* __restrict__ scores,
    const float4* __restrict__ gtb, const int* __restrict__ glab,
    float* __restrict__ out, u32* __restrict__ flags, u32* __restrict__ ws) {
#pragma clang fp contract(off)
    __shared__ float4 gA[MG];
    __shared__ int glb[MG];
    __shared__ u32 lh[2048];        // packed hist: pos low16 | neg high16
    const int bx = blockIdx.x;
    const int tid = threadIdx.x;
    const int n = bx / BPIK;
    const int kb = bx - n * BPIK;

    if (tid < 9) {
        const int i = bx * 9 + tid;       // 1876*9 = 16884 >= 16416
        if (i < LISTO) atomicExch(&ws[i], 0u);   // coherent with later atomicAdd merges
    }
    for (int i = tid; i < 2048; i += 256) lh[i] = 0;
    if (tid < MG) {
        gA[tid] = gtb[n * MG + tid];
        glb[tid] = glab[n * MG + tid];
    }
    __syncthreads();

    const int k0 = (kb * 256 + tid) * 2;   // 2 consecutive anchors (KA%2==0)
    if (k0 < KA) {
        float ax0[2], ay0[2], ax2[2], ay2[2];
        #pragma unroll
        for (int j = 0; j < 2; ++j) {
            const float4 A = anchors[k0 + j];
            ax0[j] = A.x; ay0[j] = A.y; ax2[j] = A.z; ay2[j] = A.w;
        }
        float aaw[2], aah[2], aar[2], bst[2];
        int bix[2];
        #pragma unroll
        for (int j = 0; j < 2; ++j) {
            aaw[j] = ax2[j] - ax0[j];
            aah[j] = ay2[j] - ay0[j];
            aar[j] = aaw[j] * aah[j];
            bst[j] = -1.0f;
            bix[j] = 0;
        }
        for (int m = 0; m < MG; m += 2) {
            const float4 Ga = gA[m];
            const float4 Gb = gA[m + 1];
            const float gaA = (Ga.z - Ga.x) * (Ga.w - Ga.y);   // same ops as reference
            const float gaB = (Gb.z - Gb.x) * (Gb.w - Gb.y);
            #pragma unroll
            for (int j = 0; j < 2; ++j) {
                const float wa = fmaxf(fminf(ax2[j], Ga.z) - fmaxf(ax0[j], Ga.x), 0.0f);
                const float ha = fmaxf(fminf(ay2[j], Ga.w) - fmaxf(ay0[j], Ga.y), 0.0f);
                const float ia = wa * ha;
                const float qa = ia / (((aar[j] + gaA) - ia) + 1e-8f);  // IEEE f32 div
                const float wb = fmaxf(fminf(ax2[j], Gb.z) - fmaxf(ax0[j], Gb.x), 0.0f);
                const float hb = fmaxf(fminf(ay2[j], Gb.w) - fmaxf(ay0[j], Gb.y), 0.0f);
                const float ib = wb * hb;
                const float qb = ib / (((aar[j] + gaB) - ib) + 1e-8f);
                if (qa > bst[j]) { bst[j] = qa; bix[j] = m; }       // strict >: first idx
                if (qb > bst[j]) { bst[j] = qb; bix[j] = m + 1; }
            }
        }

        const int nk = n * KA + k0;
        const float2 s2 = ((const float2*)scores)[nk >> 1];
        const float scv[2] = {s2.x, s2.y};

        float clsv[2];
        float4 regv[2];
        u32 flagpack = 0;
        #pragma unroll
        for (int j = 0; j < 2; ++j) {
            const bool pos = bst[j] >= 0.7f;
            const bool neg = bst[j] < 0.3f;
            clsv[j] = pos ? (float)glb[bix[j]] : 0.0f;
            float4 rv = make_float4(0.0f, 0.0f, 0.0f, 0.0f);
            if (pos) {
                const float4 Gm = gA[bix[j]];
                const float gw = Gm.z - Gm.x, gh = Gm.w - Gm.y;
                const float gcx = Gm.x + 0.5f * gw, gcy = Gm.y + 0.5f * gh;
                const float acx = ax0[j] + 0.5f * aaw[j], acy = ay0[j] + 0.5f * aah[j];
                rv.x = (gcx - acx) / aaw[j];
                rv.y = (gcy - acy) / aah[j];
                rv.z = logf(gw / aaw[j]);
                rv.w = logf(gh / aah[j]);
            }
            regv[j] = rv;
            const u32 fl = pos ? 1u : (neg ? 2u : 0u);
            flagpack |= fl << (8 * j);
            if (fl) atomicAdd(&lh[sortkey32(scv[j]) >> 21], fl == 2u ? 0x10000u : 1u);
        }
        const size_t NK = (size_t)NI * KA;
        const int t2 = nk >> 1;
        ((float2*)out)[t2] = make_float2(clsv[0], clsv[1]);
        float4* regp = ((float4*)(out + NK)) + nk;
        regp[0] = regv[0]; regp[1] = regv[1];
        const float2 z2 = make_float2(0.0f, 0.0f);
        ((float2*)out)[(5 * NK >> 1) + t2] = z2;   // cls_weights prewrite
        ((float2*)out)[(6 * NK >> 1) + t2] = z2;   // reg_weights prewrite
        // u16 half of the u32 flag word (lo=anchors 0,1 / hi=anchors 2,3 of nk>>2);
        // both halves written by adjacent threads of the same block (same L1).
        ((unsigned short*)flags)[t2] = (unsigned short)flagpack;
    }
    __syncthreads();
    // merge packed LDS histogram into per-group global hist
    const int gp = 2 * n;
    for (int i = tid; i < 2048; i += 256) {
        const u32 c = lh[i];
        if (c & 0xFFFFu) atomicAdd(&ws[gp * 2048 + i], c & 0xFFFFu);
        if (c >> 16)     atomicAdd(&ws[(gp + 1) * 2048 + i], c >> 16);
    }
}

// ---------------- D2: boundary scan + sparse weight patches + tie collection ----------------
__global__ void __launch_bounds__(256) kP(const float* __restrict__ scores,
                                          const u32* __restrict__ flagsW,
                                          u32* __restrict__ ws,
                                          float* __restrict__ out) {
    __shared__ u32 cs[256];
    __shared__ u32 s_us[2], s_R[2], s_done[2];
    const int bx = blockIdx.x, tid = threadIdx.x;
    const int n = bx / BPI, kb = bx - n * BPI;
    u32* hist = ws;
    u32* meta = ws + METAO;
    u32* list = ws + LISTO;

    // boundary for both groups of this image (redundant per block; hist is L2-hot)
    for (int gi = 0; gi < 2; ++gi) {
        const int g = 2 * n + gi;
        u32 loc[8];
        u32 s = 0;
        const int base = g * 2048 + tid * 8;
        #pragma unroll
        for (int j = 0; j < 8; ++j) { loc[j] = hist[base + j]; s += loc[j]; }
        cs[tid] = s;
        __syncthreads();
        for (int d = 1; d < 256; d <<= 1) {
            const u32 add = (tid + d < 256) ? cs[tid + d] : 0u;
            __syncthreads();
            cs[tid] += add;
            __syncthreads();
        }
        if (tid == 0) s_done[gi] = (cs[0] < NSEL) ? 1u : 0u;
        u32 run = (tid < 255) ? cs[tid + 1] : 0u;
        #pragma unroll
        for (int j = 7; j >= 0; --j) {
            const u32 Sj = run + loc[j];
            if (Sj >= NSEL && run < NSEL) {
                s_us[gi] = (u32)(tid * 8 + j);   // boundary 11-bit prefix
                s_R[gi] = NSEL - run;            // slots within boundary bin
            }
            run = Sj;
        }
        __syncthreads();
    }
    if (kb == 0 && tid == 0) {                   // publish for D3 (one writer/image)
        meta[2 * n] = s_us[0];     meta[8 + 2 * n] = s_R[0];     meta[16 + 2 * n] = s_done[0];
        meta[2 * n + 1] = s_us[1]; meta[8 + 2 * n + 1] = s_R[1]; meta[16 + 2 * n + 1] = s_done[1];
    }

    const int k0 = (kb * 256 + tid) * 4;
    if (k0 >= KA) return;
    const int nk = n * KA + k0;
    const u32 fw = flagsW[nk >> 2];
    if (!fw) return;                             // no members among these 4 anchors
    const float4 s4 = ((const float4*)scores)[nk >> 2];
    const float scv[4] = {s4.x, s4.y, s4.z, s4.w};
    const size_t NK = (size_t)NI * KA;
    u32* o32 = (u32*)out;
    #pragma unroll
    for (int j = 0; j < 4; ++j) {
        const u32 f = (fw >> (8 * j)) & 255u;
        if (!f) continue;
        const int gi = (f == 2u) ? 1 : 0;
        bool in = false;
        if (s_done[gi]) {
            in = true;                            // group < 256 members: take all
        } else {
            const u32 key = sortkey32(scv[j]);
            const u32 p11 = key >> 21;
            if (p11 > s_us[gi]) {
                in = true;
            } else if (p11 == s_us[gi]) {
                // boundary-bin member: defer verdict to D3 (weight stays 0)
                const int g = 2 * n + gi;
                const u32 p = atomicAdd(&meta[24 + g], 1u);
                if (p < CAPL) {
                    list[(g * CAPL + p) * 2] = key;
                    list[(g * CAPL + p) * 2 + 1] = (u32)(k0 + j);
                }
            }
        }
        if (in) {
            patch1(&o32[5 * NK + nk + j]);                 // cls_weights = 1.0
            if (f == 1u) patch1(&o32[6 * NK + nk + j]);    // reg_weights = 1.0
        }
    }
}

// ---------------- D3: boundary-bin refinement + atomic fixups (8 blocks) ----------------
__global__ void __launch_bounds__(256) kR2(const u32* __restrict__ ws,
                                           float* __restrict__ out) {
    __shared__ u32 h2[1024];
    __shared__ u32 cs[256];
    __shared__ u32 s_usb, s_R2, s_tc;
    __shared__ u32 tk[256], ti[256];
    const u32* meta = ws + METAO;
    const u32* list = ws + LISTO;
    const int g = blockIdx.x, tid = threadIdx.x;
    if (meta[16 + g]) return;                 // take-all group (uniform return)
    u32 c = meta[24 + g];
    if (c > CAPL) c = CAPL;
    const u32 R1 = meta[8 + g];
    for (u32 i = tid; i < 1024; i += 256) h2[i] = 0;
    if (tid == 0) s_tc = 0;
    __syncthreads();
    for (u32 j = tid; j < c; j += 256)
        atomicAdd(&h2[(list[(g * CAPL + j) * 2] >> 11) & 1023u], 1u);
    __syncthreads();
    // suffix scan over 1024 sub-bins
    u32 loc[4];
    u32 s = 0;
    #pragma unroll
    for (int j = 0; j < 4; ++j) { loc[j] = h2[tid * 4 + j]; s += loc[j]; }
    cs[tid] = s;
    __syncthreads();
    for (int d = 1; d < 256; d <<= 1) {
        const u32 add = (tid + d < 256) ? cs[tid + d] : 0u;
        __syncthreads();
        cs[tid] += add;
        __syncthreads();
    }
    u32 run = (tid < 255) ? cs[tid + 1] : 0u;
    #pragma unroll
    for (int j = 3; j >= 0; --j) {
        const u32 Sj = run + loc[j];
        if (Sj >= R1 && run < R1) { s_usb = (u32)(tid * 4 + j); s_R2 = R1 - run; }
        run = Sj;
    }
    __syncthreads();
    const u32 usb = s_usb, R2 = s_R2;
    const int nn = g >> 1;
    const bool posg = ((g & 1) == 0);
    const size_t NK = (size_t)NI * KA;
    u32* o32 = (u32*)out;
    for (u32 j = tid; j < c; j += 256) {
        const u32 key = list[(g * CAPL + j) * 2];
        const u32 idx = list[(g * CAPL + j) * 2 + 1];
        const u32 sb = (key >> 11) & 1023u;
        if (sb > usb) {
            const size_t o = (size_t)nn * KA + idx;
            patch1(&o32[5 * NK + o]);
            if (posg) patch1(&o32[6 * NK + o]);
        } else if (sb == usb) {
            const u32 p = atomicAdd(&s_tc, 1u);
            if (p < 256) { tk[p] = key; ti[p] = idx; }
        }
    }
    __syncthreads();
    u32 tc = s_tc;
    if (tc > 256) tc = 256;
    // rank tiny tie set by (key desc, idx asc) — stable top_k semantics
    for (u32 i = tid; i < tc; i += 256) {
        const u32 ki = tk[i], ii = ti[i];
        u32 rank = 0;
        for (u32 j = 0; j < tc; ++j) {
            const u32 kj = tk[j];
            if (kj > ki || (kj == ki && ti[j] < ii)) rank++;
        }
        if (rank < R2) {
            const size_t o = (size_t)nn * KA + ii;
            patch1(&o32[5 * NK + o]);
            if (posg) patch1(&o32[6 * NK + o]);
        }
    }
}

extern "C" void kernel_launch(void* const* d_in, const int* in_sizes, int n_in,
                              void* d_out, int out_size, void* d_ws, size_t ws_size,
                              hipStream_t stream) {
    (void)in_sizes; (void)n_in; (void)out_size; (void)ws_size;
    const float4* anchors = (const float4*)d_in[0];   // (K,4) f32
    const float*  scores  = (const float*)d_in[1];    // (N,K) f32
    const float4* gtb     = (const float4*)d_in[2];   // (N,M,4) f32
    const int*    glab    = (const int*)d_in[3];      // (N,M) int32
    float* out = (float*)d_out;

    u32* ws = (u32*)d_ws;
    u32* flags = ws + LISTO + 8 * CAPL * 2;           // u32 per 4 anchors

    AnchorTargetLayer_48052094107725_kernel<<<GRIDK, 256, 0, stream>>>(
        anchors, scores, gtb, glab, out, flags, ws);
    kP<<<GRID, 256, 0, stream>>>(scores, flags, ws, out);
    kR2<<<8, 256, 0, stream>>>(ws, out);
}

// Round 4
// 128.865 us; speedup vs baseline: 2.5145x; 1.0704x over previous
//
#include <hip/hip_runtime.h>

// Problem constants (from reference)
#define KA 240000
#define NI 4
#define MG 50
#define NSEL 256u
#define CAPL 4096          // boundary-bin member cap per group (expect ~260)
#define BPI 235            // kP blocks per image: 235*256*4 = 240640 >= 240000
#define GRID (BPI * NI)    // 940 blocks (kP)
#define BPIK 469           // K1 blocks per image: 469*256*2 = 240128 >= 240000
#define GRIDK (BPIK * NI)  // 1876 blocks (K1) -> ~7.3 blocks/CU, fills wave slots

typedef unsigned int u32;

// ws layout (u32 units): hist 8x2048 @0 | meta[32] @16384 | list @16416 (8*CAPL*2)
// meta: us[0..8) | R[8..16) | done[16..24) | cnt[24..32)
#define METAO 16384
#define LISTO (METAO + 32)
#define ONE_F 0x3F800000u   // 1.0f bits

// monotone f32 -> u32 sortkey (order-preserving for all finite floats)
static __device__ __forceinline__ u32 sortkey32(float f) {
    u32 b = __float_as_uint(f);
    return (b & 0x80000000u) ? ~b : (b | 0x80000000u);
}
// agent-scope atomic dword store: bypasses per-XCD L2, so scattered 1.0 patches
// from blocks on different XCDs can share a 64B line without lost updates.
static __device__ __forceinline__ void patch1(u32* p) {
    __hip_atomic_store(p, ONE_F, __ATOMIC_RELAXED, __HIP_MEMORY_SCOPE_AGENT);
}

// ---------------- D1: fused zero + IoU/argmax + targets + weight-prewrite + hist ----------------
// Division-free argmax: IoU_a > IoU_b  <=>  inter_a*den_b > inter_b*den_a (dens>0).
// Replaces 50 IEEE divs/anchor (~10 VALU inst each) with 2 muls + cmp per gt;
// ONE IEEE div per anchor at the end reproduces the reference quotient bit-exactly
// for the >=0.7 / <0.3 threshold tests. Init (bi=-1, bd=1) == reference bst=-1.
extern "C" __global__ void __launch_bounds__(256, 8)
AnchorTargetLayer_48052094107725_kernel(
    const float4* __restrict__ anchors, const float* __restrict__ scores,
    const float4* __restrict__ gtb, const int* __restrict__ glab,
    float* __restrict__ out, u32* __restrict__ flags, u32* __restrict__ ws) {
#pragma clang fp contract(off)
    __shared__ float4 gA[MG];
    __shared__ int glb[MG];
    __shared__ u32 lh[2048];        // packed hist: pos low16 | neg high16
    const int bx = blockIdx.x;
    const int tid = threadIdx.x;
    const int n = bx / BPIK;
    const int kb = bx - n * BPIK;

    if (tid < 9) {
        const int i = bx * 9 + tid;       // 1876*9 = 16884 >= 16416
        if (i < LISTO) atomicExch(&ws[i], 0u);   // coherent with later atomicAdd merges
    }
    for (int i = tid; i < 2048; i += 256) lh[i] = 0;
    if (tid < MG) {
        gA[tid] = gtb[n * MG + tid];
        glb[tid] = glab[n * MG + tid];
    }
    __syncthreads();

    const int k0 = (kb * 256 + tid) * 2;   // 2 consecutive anchors (KA%2==0)
    if (k0 < KA) {
        float ax0[2], ay0[2], ax2[2], ay2[2];
        #pragma unroll
        for (int j = 0; j < 2; ++j) {
            const float4 A = anchors[k0 + j];
            ax0[j] = A.x; ay0[j] = A.y; ax2[j] = A.z; ay2[j] = A.w;
        }
        float aaw[2], aah[2], aar[2];
        float bi[2], bd[2];              // inter & den of running best (q = bi/bd)
        int bix[2];
        #pragma unroll
        for (int j = 0; j < 2; ++j) {
            aaw[j] = ax2[j] - ax0[j];
            aah[j] = ay2[j] - ay0[j];
            aar[j] = aaw[j] * aah[j];
            bi[j] = -1.0f;               // implied q = -1 (matches reference bst=-1:
            bd[j] = 1.0f;                //  ia*1 >= 0 > -1*da since da>0 always here)
            bix[j] = 0;
        }
        for (int m = 0; m < MG; m += 2) {
            const float4 Ga = gA[m];
            const float4 Gb = gA[m + 1];
            const float gaA = (Ga.z - Ga.x) * (Ga.w - Ga.y);   // same ops as reference
            const float gaB = (Gb.z - Gb.x) * (Gb.w - Gb.y);
            #pragma unroll
            for (int j = 0; j < 2; ++j) {
                const float wa = fmaxf(fminf(ax2[j], Ga.z) - fmaxf(ax0[j], Ga.x), 0.0f);
                const float ha = fmaxf(fminf(ay2[j], Ga.w) - fmaxf(ay0[j], Ga.y), 0.0f);
                const float ia = wa * ha;
                const float da = ((aar[j] + gaA) - ia) + 1e-8f;   // reference denom
                if (ia * bd[j] > bi[j] * da) { bi[j] = ia; bd[j] = da; bix[j] = m; }
                const float wb = fmaxf(fminf(ax2[j], Gb.z) - fmaxf(ax0[j], Gb.x), 0.0f);
                const float hb = fmaxf(fminf(ay2[j], Gb.w) - fmaxf(ay0[j], Gb.y), 0.0f);
                const float ib = wb * hb;
                const float db = ((aar[j] + gaB) - ib) + 1e-8f;
                if (ib * bd[j] > bi[j] * db) { bi[j] = ib; bd[j] = db; bix[j] = m + 1; }
            }
        }

        const int nk = n * KA + k0;
        const float2 s2 = ((const float2*)scores)[nk >> 1];
        const float scv[2] = {s2.x, s2.y};

        float clsv[2];
        float4 regv[2];
        u32 flagpack = 0;
        #pragma unroll
        for (int j = 0; j < 2; ++j) {
            const float q = bi[j] / bd[j];       // IEEE f32 div, once per anchor:
            const bool pos = q >= 0.7f;          // bit-exact reference max quotient
            const bool neg = q < 0.3f;
            clsv[j] = pos ? (float)glb[bix[j]] : 0.0f;
            float4 rv = make_float4(0.0f, 0.0f, 0.0f, 0.0f);
            if (pos) {
                const float4 Gm = gA[bix[j]];
                const float gw = Gm.z - Gm.x, gh = Gm.w - Gm.y;
                const float gcx = Gm.x + 0.5f * gw, gcy = Gm.y + 0.5f * gh;
                const float acx = ax0[j] + 0.5f * aaw[j], acy = ay0[j] + 0.5f * aah[j];
                rv.x = (gcx - acx) / aaw[j];
                rv.y = (gcy - acy) / aah[j];
                rv.z = logf(gw / aaw[j]);
                rv.w = logf(gh / aah[j]);
            }
            regv[j] = rv;
            const u32 fl = pos ? 1u : (neg ? 2u : 0u);
            flagpack |= fl << (8 * j);
            if (fl) atomicAdd(&lh[sortkey32(scv[j]) >> 21], fl == 2u ? 0x10000u : 1u);
        }
        const size_t NK = (size_t)NI * KA;
        const int t2 = nk >> 1;
        ((float2*)out)[t2] = make_float2(clsv[0], clsv[1]);
        float4* regp = ((float4*)(out + NK)) + nk;
        regp[0] = regv[0]; regp[1] = regv[1];
        const float2 z2 = make_float2(0.0f, 0.0f);
        ((float2*)out)[(5 * NK >> 1) + t2] = z2;   // cls_weights prewrite
        ((float2*)out)[(6 * NK >> 1) + t2] = z2;   // reg_weights prewrite
        // u16 half of the u32 flag word (lo=anchors 0,1 / hi=anchors 2,3 of nk>>2);
        // both halves written by adjacent threads of the same block (same L1).
        ((unsigned short*)flags)[t2] = (unsigned short)flagpack;
    }
    __syncthreads();
    // merge packed LDS histogram into per-group global hist
    const int gp = 2 * n;
    for (int i = tid; i < 2048; i += 256) {
        const u32 c = lh[i];
        if (c & 0xFFFFu) atomicAdd(&ws[gp * 2048 + i], c & 0xFFFFu);
        if (c >> 16)     atomicAdd(&ws[(gp + 1) * 2048 + i], c >> 16);
    }
}

// ---------------- D2: boundary scan + sparse weight patches + tie collection ----------------
__global__ void __launch_bounds__(256) kP(const float* __restrict__ scores,
                                          const u32* __restrict__ flagsW,
                                          u32* __restrict__ ws,
                                          float* __restrict__ out) {
    __shared__ u32 cs[256];
    __shared__ u32 s_us[2], s_R[2], s_done[2];
    const int bx = blockIdx.x, tid = threadIdx.x;
    const int n = bx / BPI, kb = bx - n * BPI;
    u32* hist = ws;
    u32* meta = ws + METAO;
    u32* list = ws + LISTO;

    // boundary for both groups of this image (redundant per block; hist is L2-hot)
    for (int gi = 0; gi < 2; ++gi) {
        const int g = 2 * n + gi;
        u32 loc[8];
        u32 s = 0;
        const int base = g * 2048 + tid * 8;
        #pragma unroll
        for (int j = 0; j < 8; ++j) { loc[j] = hist[base + j]; s += loc[j]; }
        cs[tid] = s;
        __syncthreads();
        for (int d = 1; d < 256; d <<= 1) {
            const u32 add = (tid + d < 256) ? cs[tid + d] : 0u;
            __syncthreads();
            cs[tid] += add;
            __syncthreads();
        }
        if (tid == 0) s_done[gi] = (cs[0] < NSEL) ? 1u : 0u;
        u32 run = (tid < 255) ? cs[tid + 1] : 0u;
        #pragma unroll
        for (int j = 7; j >= 0; --j) {
            const u32 Sj = run + loc[j];
            if (Sj >= NSEL && run < NSEL) {
                s_us[gi] = (u32)(tid * 8 + j);   // boundary 11-bit prefix
                s_R[gi] = NSEL - run;            // slots within boundary bin
            }
            run = Sj;
        }
        __syncthreads();
    }
    if (kb == 0 && tid == 0) {                   // publish for D3 (one writer/image)
        meta[2 * n] = s_us[0];     meta[8 + 2 * n] = s_R[0];     meta[16 + 2 * n] = s_done[0];
        meta[2 * n + 1] = s_us[1]; meta[8 + 2 * n + 1] = s_R[1]; meta[16 + 2 * n + 1] = s_done[1];
    }

    const int k0 = (kb * 256 + tid) * 4;
    if (k0 >= KA) return;
    const int nk = n * KA + k0;
    const u32 fw = flagsW[nk >> 2];
    if (!fw) return;                             // no members among these 4 anchors
    const float4 s4 = ((const float4*)scores)[nk >> 2];
    const float scv[4] = {s4.x, s4.y, s4.z, s4.w};
    const size_t NK = (size_t)NI * KA;
    u32* o32 = (u32*)out;
    #pragma unroll
    for (int j = 0; j < 4; ++j) {
        const u32 f = (fw >> (8 * j)) & 255u;
        if (!f) continue;
        const int gi = (f == 2u) ? 1 : 0;
        bool in = false;
        if (s_done[gi]) {
            in = true;                            // group < 256 members: take all
        } else {
            const u32 key = sortkey32(scv[j]);
            const u32 p11 = key >> 21;
            if (p11 > s_us[gi]) {
                in = true;
            } else if (p11 == s_us[gi]) {
                // boundary-bin member: defer verdict to D3 (weight stays 0)
                const int g = 2 * n + gi;
                const u32 p = atomicAdd(&meta[24 + g], 1u);
                if (p < CAPL) {
                    list[(g * CAPL + p) * 2] = key;
                    list[(g * CAPL + p) * 2 + 1] = (u32)(k0 + j);
                }
            }
        }
        if (in) {
            patch1(&o32[5 * NK + nk + j]);                 // cls_weights = 1.0
            if (f == 1u) patch1(&o32[6 * NK + nk + j]);    // reg_weights = 1.0
        }
    }
}

// ---------------- D3: boundary-bin refinement + atomic fixups (8 blocks) ----------------
__global__ void __launch_bounds__(256) kR2(const u32* __restrict__ ws,
                                           float* __restrict__ out) {
    __shared__ u32 h2[1024];
    __shared__ u32 cs[256];
    __shared__ u32 s_usb, s_R2, s_tc;
    __shared__ u32 tk[256], ti[256];
    const u32* meta = ws + METAO;
    const u32* list = ws + LISTO;
    const int g = blockIdx.x, tid = threadIdx.x;
    if (meta[16 + g]) return;                 // take-all group (uniform return)
    u32 c = meta[24 + g];
    if (c > CAPL) c = CAPL;
    const u32 R1 = meta[8 + g];
    for (u32 i = tid; i < 1024; i += 256) h2[i] = 0;
    if (tid == 0) s_tc = 0;
    __syncthreads();
    for (u32 j = tid; j < c; j += 256)
        atomicAdd(&h2[(list[(g * CAPL + j) * 2] >> 11) & 1023u], 1u);
    __syncthreads();
    // suffix scan over 1024 sub-bins
    u32 loc[4];
    u32 s = 0;
    #pragma unroll
    for (int j = 0; j < 4; ++j) { loc[j] = h2[tid * 4 + j]; s += loc[j]; }
    cs[tid] = s;
    __syncthreads();
    for (int d = 1; d < 256; d <<= 1) {
        const u32 add = (tid + d < 256) ? cs[tid + d] : 0u;
        __syncthreads();
        cs[tid] += add;
        __syncthreads();
    }
    u32 run = (tid < 255) ? cs[tid + 1] : 0u;
    #pragma unroll
    for (int j = 3; j >= 0; --j) {
        const u32 Sj = run + loc[j];
        if (Sj >= R1 && run < R1) { s_usb = (u32)(tid * 4 + j); s_R2 = R1 - run; }
        run = Sj;
    }
    __syncthreads();
    const u32 usb = s_usb, R2 = s_R2;
    const int nn = g >> 1;
    const bool posg = ((g & 1) == 0);
    const size_t NK = (size_t)NI * KA;
    u32* o32 = (u32*)out;
    for (u32 j = tid; j < c; j += 256) {
        const u32 key = list[(g * CAPL + j) * 2];
        const u32 idx = list[(g * CAPL + j) * 2 + 1];
        const u32 sb = (key >> 11) & 1023u;
        if (sb > usb) {
            const size_t o = (size_t)nn * KA + idx;
            patch1(&o32[5 * NK + o]);
            if (posg) patch1(&o32[6 * NK + o]);
        } else if (sb == usb) {
            const u32 p = atomicAdd(&s_tc, 1u);
            if (p < 256) { tk[p] = key; ti[p] = idx; }
        }
    }
    __syncthreads();
    u32 tc = s_tc;
    if (tc > 256) tc = 256;
    // rank tiny tie set by (key desc, idx asc) — stable top_k semantics
    for (u32 i = tid; i < tc; i += 256) {
        const u32 ki = tk[i], ii = ti[i];
        u32 rank = 0;
        for (u32 j = 0; j < tc; ++j) {
            const u32 kj = tk[j];
            if (kj > ki || (kj == ki && ti[j] < ii)) rank++;
        }
        if (rank < R2) {
            const size_t o = (size_t)nn * KA + ii;
            patch1(&o32[5 * NK + o]);
            if (posg) patch1(&o32[6 * NK + o]);
        }
    }
}

extern "C" void kernel_launch(void* const* d_in, const int* in_sizes, int n_in,
                              void* d_out, int out_size, void* d_ws, size_t ws_size,
                              hipStream_t stream) {
    (void)in_sizes; (void)n_in; (void)out_size; (void)ws_size;
    const float4* anchors = (const float4*)d_in[0];   // (K,4) f32
    const float*  scores  = (const float*)d_in[1];    // (N,K) f32
    const float4* gtb     = (const float4*)d_in[2];   // (N,M,4) f32
    const int*    glab    = (const int*)d_in[3];      // (N,M) int32
    float* out = (float*)d_out;

    u32* ws = (u32*)d_ws;
    u32* flags = ws + LISTO + 8 * CAPL * 2;           // u32 per 4 anchors

    AnchorTargetLayer_48052094107725_kernel<<<GRIDK, 256, 0, stream>>>(
        anchors, scores, gtb, glab, out, flags, ws);
    kP<<<GRID, 256, 0, stream>>>(scores, flags, ws, out);
    kR2<<<8, 256, 0, stream>>>(ws, out);
}

// Round 5
// 126.631 us; speedup vs baseline: 2.5588x; 1.0176x over previous
//
#include <hip/hip_runtime.h>

// Problem constants (from reference)
#define KA 240000
#define NI 4
#define MG 50
#define NSEL 256u
#define CAPL 4096          // boundary-bin member cap per group (expect ~260)
#define BPI 235            // kP blocks per image: 235*256*4 = 240640 >= 240000
#define GRID (BPI * NI)    // 940 blocks (kP)
#define BPIK 469           // K1 blocks per image: 469*256*2 = 240128 >= 240000
#define GRIDK (BPIK * NI)  // 1876 blocks (K1) -> ~7.3 blocks/CU, fills wave slots

typedef unsigned int u32;

// ws layout (u32 units): hist 8x2048 @0 | meta[32] @16384 | list @16416 (8*CAPL*2)
// meta: us[0..8) | R[8..16) | done[16..24) | cnt[24..32)
#define METAO 16384
#define LISTO (METAO + 32)
#define ONE_F 0x3F800000u   // 1.0f bits

// monotone f32 -> u32 sortkey (order-preserving for all finite floats)
static __device__ __forceinline__ u32 sortkey32(float f) {
    u32 b = __float_as_uint(f);
    return (b & 0x80000000u) ? ~b : (b | 0x80000000u);
}
// agent-scope atomic dword store: bypasses per-XCD L2, so scattered 1.0 patches
// from blocks on different XCDs can share a 64B line without lost updates.
static __device__ __forceinline__ void patch1(u32* p) {
    __hip_atomic_store(p, ONE_F, __ATOMIC_RELAXED, __HIP_MEMORY_SCOPE_AGENT);
}

// ---------------- D1: fused zero + IoU/argmax + targets + weight-prewrite + hist ----------------
// Division-free argmax (round 4) + two ILP upgrades:
//  - per-gt areas hoisted to LDS (gar[]): 6 VALU inst/iter moved to the idle LDS pipe
//  - even/odd gt split: 4 independent argmax chains per thread (was 2 serial ones),
//    halving the exposed mul->cmp->cndmask dependency latency; merged per anchor with
//    the same cross-product comparator + smaller-index tie-break (reproduces the
//    reference first-max: all-zero anchors tie at 0 and resolve to index 0).
// ONE IEEE div per anchor reproduces the reference quotient bit-exactly for the
// >=0.7 / <0.3 threshold tests.
extern "C" __global__ void __launch_bounds__(256, 8)
AnchorTargetLayer_48052094107725_kernel(
    const float4* __restrict__ anchors, const float* __restrict__ scores,
    const float4* __restrict__ gtb, const int* __restrict__ glab,
    float* __restrict__ out, u32* __restrict__ flags, u32* __restrict__ ws) {
#pragma clang fp contract(off)
    __shared__ float4 gA[MG];
    __shared__ float gar[MG];
    __shared__ int glb[MG];
    __shared__ u32 lh[2048];        // packed hist: pos low16 | neg high16
    const int bx = blockIdx.x;
    const int tid = threadIdx.x;
    const int n = bx / BPIK;
    const int kb = bx - n * BPIK;

    if (tid < 9) {
        const int i = bx * 9 + tid;       // 1876*9 = 16884 >= 16416
        if (i < LISTO) atomicExch(&ws[i], 0u);   // coherent with later atomicAdd merges
    }
    for (int i = tid; i < 2048; i += 256) lh[i] = 0;
    if (tid < MG) {
        const float4 G = gtb[n * MG + tid];
        gA[tid] = G;
        gar[tid] = (G.z - G.x) * (G.w - G.y);   // same ops as reference area_g
        glb[tid] = glab[n * MG + tid];
    }
    __syncthreads();

    const int k0 = (kb * 256 + tid) * 2;   // 2 consecutive anchors (KA%2==0)
    if (k0 < KA) {
        float ax0[2], ay0[2], ax2[2], ay2[2];
        #pragma unroll
        for (int j = 0; j < 2; ++j) {
            const float4 A = anchors[k0 + j];
            ax0[j] = A.x; ay0[j] = A.y; ax2[j] = A.z; ay2[j] = A.w;
        }
        float aaw[2], aah[2], aar[2];
        float biE[2], bdE[2], biO[2], bdO[2];   // even/odd chains: q = bi/bd
        int bixE[2], bixO[2];
        #pragma unroll
        for (int j = 0; j < 2; ++j) {
            aaw[j] = ax2[j] - ax0[j];
            aah[j] = ay2[j] - ay0[j];
            aar[j] = aaw[j] * aah[j];
            biE[j] = -1.0f; bdE[j] = 1.0f; bixE[j] = 0;   // implied q=-1; first gt of
            biO[j] = -1.0f; bdO[j] = 1.0f; bixO[j] = 1;   // each chain always wins it
        }
        #pragma unroll 5
        for (int m = 0; m < MG; m += 2) {
            const float4 Ga = gA[m];
            const float4 Gb = gA[m + 1];
            const float gaA = gar[m];       // hoisted per-gt area (LDS broadcast)
            const float gaB = gar[m + 1];
            #pragma unroll
            for (int j = 0; j < 2; ++j) {
                const float wa = fmaxf(fminf(ax2[j], Ga.z) - fmaxf(ax0[j], Ga.x), 0.0f);
                const float ha = fmaxf(fminf(ay2[j], Ga.w) - fmaxf(ay0[j], Ga.y), 0.0f);
                const float ia = wa * ha;
                const float da = ((aar[j] + gaA) - ia) + 1e-8f;   // reference denom
                if (ia * bdE[j] > biE[j] * da) { biE[j] = ia; bdE[j] = da; bixE[j] = m; }
                const float wb = fmaxf(fminf(ax2[j], Gb.z) - fmaxf(ax0[j], Gb.x), 0.0f);
                const float hb = fmaxf(fminf(ay2[j], Gb.w) - fmaxf(ay0[j], Gb.y), 0.0f);
                const float ib = wb * hb;
                const float db = ((aar[j] + gaB) - ib) + 1e-8f;
                if (ib * bdO[j] > biO[j] * db) { biO[j] = ib; bdO[j] = db; bixO[j] = m + 1; }
            }
        }

        const int nk = n * KA + k0;
        const float2 s2 = ((const float2*)scores)[nk >> 1];
        const float scv[2] = {s2.x, s2.y};

        float clsv[2];
        float4 regv[2];
        u32 flagpack = 0;
        #pragma unroll
        for (int j = 0; j < 2; ++j) {
            // merge even/odd chains: qO > qE <=> biO*bdE > biE*bdO (bd > 0);
            // exact product tie -> smaller index (reference first-max semantics)
            const float pO = biO[j] * bdE[j];
            const float pE = biE[j] * bdO[j];
            const bool takeO = (pO > pE) || (pO == pE && bixO[j] < bixE[j]);
            const float bi = takeO ? biO[j] : biE[j];
            const float bd = takeO ? bdO[j] : bdE[j];
            const int  bix = takeO ? bixO[j] : bixE[j];
            const float q = bi / bd;             // IEEE f32 div, once per anchor:
            const bool pos = q >= 0.7f;          // bit-exact reference max quotient
            const bool neg = q < 0.3f;
            clsv[j] = pos ? (float)glb[bix] : 0.0f;
            float4 rv = make_float4(0.0f, 0.0f, 0.0f, 0.0f);
            if (pos) {
                const float4 Gm = gA[bix];
                const float gw = Gm.z - Gm.x, gh = Gm.w - Gm.y;
                const float gcx = Gm.x + 0.5f * gw, gcy = Gm.y + 0.5f * gh;
                const float acx = ax0[j] + 0.5f * aaw[j], acy = ay0[j] + 0.5f * aah[j];
                rv.x = (gcx - acx) / aaw[j];
                rv.y = (gcy - acy) / aah[j];
                rv.z = logf(gw / aaw[j]);
                rv.w = logf(gh / aah[j]);
            }
            regv[j] = rv;
            const u32 fl = pos ? 1u : (neg ? 2u : 0u);
            flagpack |= fl << (8 * j);
            if (fl) atomicAdd(&lh[sortkey32(scv[j]) >> 21], fl == 2u ? 0x10000u : 1u);
        }
        const size_t NK = (size_t)NI * KA;
        const int t2 = nk >> 1;
        ((float2*)out)[t2] = make_float2(clsv[0], clsv[1]);
        float4* regp = ((float4*)(out + NK)) + nk;
        regp[0] = regv[0]; regp[1] = regv[1];
        const float2 z2 = make_float2(0.0f, 0.0f);
        ((float2*)out)[(5 * NK >> 1) + t2] = z2;   // cls_weights prewrite
        ((float2*)out)[(6 * NK >> 1) + t2] = z2;   // reg_weights prewrite
        // u16 half of the u32 flag word (lo=anchors 0,1 / hi=anchors 2,3 of nk>>2);
        // both halves written by adjacent threads of the same block (same L1).
        ((unsigned short*)flags)[t2] = (unsigned short)flagpack;
    }
    __syncthreads();
    // merge packed LDS histogram into per-group global hist
    const int gp = 2 * n;
    for (int i = tid; i < 2048; i += 256) {
        const u32 c = lh[i];
        if (c & 0xFFFFu) atomicAdd(&ws[gp * 2048 + i], c & 0xFFFFu);
        if (c >> 16)     atomicAdd(&ws[(gp + 1) * 2048 + i], c >> 16);
    }
}

// ---------------- D2: boundary scan + sparse weight patches + tie collection ----------------
__global__ void __launch_bounds__(256) kP(const float* __restrict__ scores,
                                          const u32* __restrict__ flagsW,
                                          u32* __restrict__ ws,
                                          float* __restrict__ out) {
    __shared__ u32 cs[256];
    __shared__ u32 s_us[2], s_R[2], s_done[2];
    const int bx = blockIdx.x, tid = threadIdx.x;
    const int n = bx / BPI, kb = bx - n * BPI;
    u32* hist = ws;
    u32* meta = ws + METAO;
    u32* list = ws + LISTO;

    // boundary for both groups of this image (redundant per block; hist is L2-hot)
    for (int gi = 0; gi < 2; ++gi) {
        const int g = 2 * n + gi;
        u32 loc[8];
        u32 s = 0;
        const int base = g * 2048 + tid * 8;
        #pragma unroll
        for (int j = 0; j < 8; ++j) { loc[j] = hist[base + j]; s += loc[j]; }
        cs[tid] = s;
        __syncthreads();
        for (int d = 1; d < 256; d <<= 1) {
            const u32 add = (tid + d < 256) ? cs[tid + d] : 0u;
            __syncthreads();
            cs[tid] += add;
            __syncthreads();
        }
        if (tid == 0) s_done[gi] = (cs[0] < NSEL) ? 1u : 0u;
        u32 run = (tid < 255) ? cs[tid + 1] : 0u;
        #pragma unroll
        for (int j = 7; j >= 0; --j) {
            const u32 Sj = run + loc[j];
            if (Sj >= NSEL && run < NSEL) {
                s_us[gi] = (u32)(tid * 8 + j);   // boundary 11-bit prefix
                s_R[gi] = NSEL - run;            // slots within boundary bin
            }
            run = Sj;
        }
        __syncthreads();
    }
    if (kb == 0 && tid == 0) {                   // publish for D3 (one writer/image)
        meta[2 * n] = s_us[0];     meta[8 + 2 * n] = s_R[0];     meta[16 + 2 * n] = s_done[0];
        meta[2 * n + 1] = s_us[1]; meta[8 + 2 * n + 1] = s_R[1]; meta[16 + 2 * n + 1] = s_done[1];
    }

    const int k0 = (kb * 256 + tid) * 4;
    if (k0 >= KA) return;
    const int nk = n * KA + k0;
    const u32 fw = flagsW[nk >> 2];
    if (!fw) return;                             // no members among these 4 anchors
    const float4 s4 = ((const float4*)scores)[nk >> 2];
    const float scv[4] = {s4.x, s4.y, s4.z, s4.w};
    const size_t NK = (size_t)NI * KA;
    u32* o32 = (u32*)out;
    #pragma unroll
    for (int j = 0; j < 4; ++j) {
        const u32 f = (fw >> (8 * j)) & 255u;
        if (!f) continue;
        const int gi = (f == 2u) ? 1 : 0;
        bool in = false;
        if (s_done[gi]) {
            in = true;                            // group < 256 members: take all
        } else {
            const u32 key = sortkey32(scv[j]);
            const u32 p11 = key >> 21;
            if (p11 > s_us[gi]) {
                in = true;
            } else if (p11 == s_us[gi]) {
                // boundary-bin member: defer verdict to D3 (weight stays 0)
                const int g = 2 * n + gi;
                const u32 p = atomicAdd(&meta[24 + g], 1u);
                if (p < CAPL) {
                    list[(g * CAPL + p) * 2] = key;
                    list[(g * CAPL + p) * 2 + 1] = (u32)(k0 + j);
                }
            }
        }
        if (in) {
            patch1(&o32[5 * NK + nk + j]);                 // cls_weights = 1.0
            if (f == 1u) patch1(&o32[6 * NK + nk + j]);    // reg_weights = 1.0
        }
    }
}

// ---------------- D3: boundary-bin refinement + atomic fixups (8 blocks) ----------------
__global__ void __launch_bounds__(256) kR2(const u32* __restrict__ ws,
                                           float* __restrict__ out) {
    __shared__ u32 h2[1024];
    __shared__ u32 cs[256];
    __shared__ u32 s_usb, s_R2, s_tc;
    __shared__ u32 tk[256], ti[256];
    const u32* meta = ws + METAO;
    const u32* list = ws + LISTO;
    const int g = blockIdx.x, tid = threadIdx.x;
    if (meta[16 + g]) return;                 // take-all group (uniform return)
    u32 c = meta[24 + g];
    if (c > CAPL) c = CAPL;
    const u32 R1 = meta[8 + g];
    for (u32 i = tid; i < 1024; i += 256) h2[i] = 0;
    if (tid == 0) s_tc = 0;
    __syncthreads();
    for (u32 j = tid; j < c; j += 256)
        atomicAdd(&h2[(list[(g * CAPL + j) * 2] >> 11) & 1023u], 1u);
    __syncthreads();
    // suffix scan over 1024 sub-bins
    u32 loc[4];
    u32 s = 0;
    #pragma unroll
    for (int j = 0; j < 4; ++j) { loc[j] = h2[tid * 4 + j]; s += loc[j]; }
    cs[tid] = s;
    __syncthreads();
    for (int d = 1; d < 256; d <<= 1) {
        const u32 add = (tid + d < 256) ? cs[tid + d] : 0u;
        __syncthreads();
        cs[tid] += add;
        __syncthreads();
    }
    u32 run = (tid < 255) ? cs[tid + 1] : 0u;
    #pragma unroll
    for (int j = 3; j >= 0; --j) {
        const u32 Sj = run + loc[j];
        if (Sj >= R1 && run < R1) { s_usb = (u32)(tid * 4 + j); s_R2 = R1 - run; }
        run = Sj;
    }
    __syncthreads();
    const u32 usb = s_usb, R2 = s_R2;
    const int nn = g >> 1;
    const bool posg = ((g & 1) == 0);
    const size_t NK = (size_t)NI * KA;
    u32* o32 = (u32*)out;
    for (u32 j = tid; j < c; j += 256) {
        const u32 key = list[(g * CAPL + j) * 2];
        const u32 idx = list[(g * CAPL + j) * 2 + 1];
        const u32 sb = (key >> 11) & 1023u;
        if (sb > usb) {
            const size_t o = (size_t)nn * KA + idx;
            patch1(&o32[5 * NK + o]);
            if (posg) patch1(&o32[6 * NK + o]);
        } else if (sb == usb) {
            const u32 p = atomicAdd(&s_tc, 1u);
            if (p < 256) { tk[p] = key; ti[p] = idx; }
        }
    }
    __syncthreads();
    u32 tc = s_tc;
    if (tc > 256) tc = 256;
    // rank tiny tie set by (key desc, idx asc) — stable top_k semantics
    for (u32 i = tid; i < tc; i += 256) {
        const u32 ki = tk[i], ii = ti[i];
        u32 rank = 0;
        for (u32 j = 0; j < tc; ++j) {
            const u32 kj = tk[j];
            if (kj > ki || (kj == ki && ti[j] < ii)) rank++;
        }
        if (rank < R2) {
            const size_t o = (size_t)nn * KA + ii;
            patch1(&o32[5 * NK + o]);
            if (posg) patch1(&o32[6 * NK + o]);
        }
    }
}

extern "C" void kernel_launch(void* const* d_in, const int* in_sizes, int n_in,
                              void* d_out, int out_size, void* d_ws, size_t ws_size,
                              hipStream_t stream) {
    (void)in_sizes; (void)n_in; (void)out_size; (void)ws_size;
    const float4* anchors = (const float4*)d_in[0];   // (K,4) f32
    const float*  scores  = (const float*)d_in[1];    // (N,K) f32
    const float4* gtb     = (const float4*)d_in[2];   // (N,M,4) f32
    const int*    glab    = (const int*)d_in[3];      // (N,M) int32
    float* out = (float*)d_out;

    u32* ws = (u32*)d_ws;
    u32* flags = ws + LISTO + 8 * CAPL * 2;           // u32 per 4 anchors

    AnchorTargetLayer_48052094107725_kernel<<<GRIDK, 256, 0, stream>>>(
        anchors, scores, gtb, glab, out, flags, ws);
    kP<<<GRID, 256, 0, stream>>>(scores, flags, ws, out);
    kR2<<<8, 256, 0, stream>>>(ws, out);
}

// Round 6
// 125.742 us; speedup vs baseline: 2.5769x; 1.0071x over previous
//
#include <hip/hip_runtime.h>

// Problem constants (from reference)
#define KA 240000
#define NI 4
#define MG 50
#define NSEL 256u
#define CAPL 4096          // boundary-bin member cap per group (expect ~260)
#define BPI 235            // kP blocks per image: 235*256*4 = 240640 >= 240000
#define GRID (BPI * NI)    // 940 blocks (kP)
#define BPIK 469           // K1 blocks per image: 469*256*2 = 240128 >= 240000
#define GRIDK (BPIK * NI)  // 1876 blocks (K1) -> ~7.3 blocks/CU, fills wave slots

typedef unsigned int u32;

// ws layout (u32 units): hist 8x2048 @0 | meta[32] @16384 | list @16416 (8*CAPL*2)
// meta: us[0..8) | R[8..16) | done[16..24) | cnt[24..32)
#define METAO 16384
#define LISTO (METAO + 32)
#define ONE_F 0x3F800000u   // 1.0f bits

// monotone f32 -> u32 sortkey (order-preserving for all finite floats)
static __device__ __forceinline__ u32 sortkey32(float f) {
    u32 b = __float_as_uint(f);
    return (b & 0x80000000u) ? ~b : (b | 0x80000000u);
}
// agent-scope atomic dword store: bypasses per-XCD L2, so scattered 1.0 patches
// from blocks on different XCDs can share a 64B line without lost updates.
static __device__ __forceinline__ void patch1(u32* p) {
    __hip_atomic_store(p, ONE_F, __ATOMIC_RELAXED, __HIP_MEMORY_SCOPE_AGENT);
}

// ---------------- D1: fused zero + IoU/argmax + targets + weight-prewrite + hist ----------------
// Denominator-free argmax: for positive dens, I1/(S1-I1) > I2/(S2-I2) <=> I1*S2 > I2*S1
// (the -I cross terms cancel exactly). So the running best tracks (I, S=ar+gar, idx)
// and each gt costs 1 add for the key instead of 3 for the full denominator.
// eps (1e-8) shifts quotients ~1e-10 relative (< f32 ulp) — ordering unaffected
// outside the sub-ulp tie class already accepted (passed rounds 4-5).
// The winner's denominator is then recomputed with the exact reference rounding
// (((aar+gar[bix])-bi)+1e-8) and ONE IEEE div reproduces the reference max
// quotient bit-exactly for the >=0.7 / <0.3 threshold tests.
extern "C" __global__ void __launch_bounds__(256, 8)
AnchorTargetLayer_48052094107725_kernel(
    const float4* __restrict__ anchors, const float* __restrict__ scores,
    const float4* __restrict__ gtb, const int* __restrict__ glab,
    float* __restrict__ out, u32* __restrict__ flags, u32* __restrict__ ws) {
#pragma clang fp contract(off)
    __shared__ float4 gA[MG];
    __shared__ float gar[MG];
    __shared__ int glb[MG];
    __shared__ u32 lh[2048];        // packed hist: pos low16 | neg high16
    const int bx = blockIdx.x;
    const int tid = threadIdx.x;
    const int n = bx / BPIK;
    const int kb = bx - n * BPIK;

    if (tid < 9) {
        const int i = bx * 9 + tid;       // 1876*9 = 16884 >= 16416
        if (i < LISTO) atomicExch(&ws[i], 0u);   // coherent with later atomicAdd merges
    }
    for (int i = tid; i < 2048; i += 256) lh[i] = 0;
    if (tid < MG) {
        const float4 G = gtb[n * MG + tid];
        gA[tid] = G;
        gar[tid] = (G.z - G.x) * (G.w - G.y);   // same ops as reference area_g
        glb[tid] = glab[n * MG + tid];
    }
    __syncthreads();

    const int k0 = (kb * 256 + tid) * 2;   // 2 consecutive anchors (KA%2==0)
    if (k0 < KA) {
        float ax0[2], ay0[2], ax2[2], ay2[2];
        #pragma unroll
        for (int j = 0; j < 2; ++j) {
            const float4 A = anchors[k0 + j];
            ax0[j] = A.x; ay0[j] = A.y; ax2[j] = A.z; ay2[j] = A.w;
        }
        float aaw[2], aah[2], aar[2];
        float biE[2], bSE[2], biO[2], bSO[2];   // even/odd chains: key q ~ bi/bS
        int bixE[2], bixO[2];
        #pragma unroll
        for (int j = 0; j < 2; ++j) {
            aaw[j] = ax2[j] - ax0[j];
            aah[j] = ay2[j] - ay0[j];
            aar[j] = aaw[j] * aah[j];
            biE[j] = -1.0f; bSE[j] = 1.0f; bixE[j] = 0;   // implied key=-1; first gt of
            biO[j] = -1.0f; bSO[j] = 1.0f; bixO[j] = 1;   // each chain always wins it
        }
        #pragma unroll 5
        for (int m = 0; m < MG; m += 2) {
            const float4 Ga = gA[m];
            const float4 Gb = gA[m + 1];
            const float gaA = gar[m];       // hoisted per-gt area (LDS broadcast)
            const float gaB = gar[m + 1];
            #pragma unroll
            for (int j = 0; j < 2; ++j) {
                const float wa = fmaxf(fminf(ax2[j], Ga.z) - fmaxf(ax0[j], Ga.x), 0.0f);
                const float ha = fmaxf(fminf(ay2[j], Ga.w) - fmaxf(ay0[j], Ga.y), 0.0f);
                const float ia = wa * ha;
                const float sa = aar[j] + gaA;   // compare key denom (no -I, no eps)
                if (ia * bSE[j] > biE[j] * sa) { biE[j] = ia; bSE[j] = sa; bixE[j] = m; }
                const float wb = fmaxf(fminf(ax2[j], Gb.z) - fmaxf(ax0[j], Gb.x), 0.0f);
                const float hb = fmaxf(fminf(ay2[j], Gb.w) - fmaxf(ay0[j], Gb.y), 0.0f);
                const float ib = wb * hb;
                const float sb = aar[j] + gaB;
                if (ib * bSO[j] > biO[j] * sb) { biO[j] = ib; bSO[j] = sb; bixO[j] = m + 1; }
            }
        }

        const int nk = n * KA + k0;
        const float2 s2 = ((const float2*)scores)[nk >> 1];
        const float scv[2] = {s2.x, s2.y};

        float clsv[2];
        float4 regv[2];
        u32 flagpack = 0;
        #pragma unroll
        for (int j = 0; j < 2; ++j) {
            // merge even/odd chains: qO > qE <=> biO*bSE > biE*bSO (bS > 0);
            // exact product tie -> smaller index (reference first-max semantics)
            const float pO = biO[j] * bSE[j];
            const float pE = biE[j] * bSO[j];
            const bool takeO = (pO > pE) || (pO == pE && bixO[j] < bixE[j]);
            const float bi = takeO ? biO[j] : biE[j];
            const int  bix = takeO ? bixO[j] : bixE[j];
            // reference-exact denominator for the winner, then one IEEE div
            const float da = ((aar[j] + gar[bix]) - bi) + 1e-8f;
            const float q = bi / da;             // bit-exact reference max quotient
            const bool pos = q >= 0.7f;
            const bool neg = q < 0.3f;
            clsv[j] = pos ? (float)glb[bix] : 0.0f;
            float4 rv = make_float4(0.0f, 0.0f, 0.0f, 0.0f);
            if (pos) {
                const float4 Gm = gA[bix];
                const float gw = Gm.z - Gm.x, gh = Gm.w - Gm.y;
                const float gcx = Gm.x + 0.5f * gw, gcy = Gm.y + 0.5f * gh;
                const float acx = ax0[j] + 0.5f * aaw[j], acy = ay0[j] + 0.5f * aah[j];
                rv.x = (gcx - acx) / aaw[j];
                rv.y = (gcy - acy) / aah[j];
                rv.z = logf(gw / aaw[j]);
                rv.w = logf(gh / aah[j]);
            }
            regv[j] = rv;
            const u32 fl = pos ? 1u : (neg ? 2u : 0u);
            flagpack |= fl << (8 * j);
            if (fl) atomicAdd(&lh[sortkey32(scv[j]) >> 21], fl == 2u ? 0x10000u : 1u);
        }
        const size_t NK = (size_t)NI * KA;
        const int t2 = nk >> 1;
        ((float2*)out)[t2] = make_float2(clsv[0], clsv[1]);
        float4* regp = ((float4*)(out + NK)) + nk;
        regp[0] = regv[0]; regp[1] = regv[1];
        const float2 z2 = make_float2(0.0f, 0.0f);
        ((float2*)out)[(5 * NK >> 1) + t2] = z2;   // cls_weights prewrite
        ((float2*)out)[(6 * NK >> 1) + t2] = z2;   // reg_weights prewrite
        // u16 half of the u32 flag word (lo=anchors 0,1 / hi=anchors 2,3 of nk>>2);
        // both halves written by adjacent threads of the same block (same L1).
        ((unsigned short*)flags)[t2] = (unsigned short)flagpack;
    }
    __syncthreads();
    // merge packed LDS histogram into per-group global hist
    const int gp = 2 * n;
    for (int i = tid; i < 2048; i += 256) {
        const u32 c = lh[i];
        if (c & 0xFFFFu) atomicAdd(&ws[gp * 2048 + i], c & 0xFFFFu);
        if (c >> 16)     atomicAdd(&ws[(gp + 1) * 2048 + i], c >> 16);
    }
}

// ---------------- D2: boundary scan + sparse weight patches + tie collection ----------------
// Scan rewritten: wave-level __shfl_down suffix scan (barrier-free) + 4-entry
// cross-wave combine — 2 barriers/group instead of ~24. Integer-exact, produces
// the identical `run` values as the old 256-thread ladder.
__global__ void __launch_bounds__(256) kP(const float* __restrict__ scores,
                                          const u32* __restrict__ flagsW,
                                          u32* __restrict__ ws,
                                          float* __restrict__ out) {
    __shared__ u32 wsum[4];
    __shared__ u32 s_us[2], s_R[2], s_done[2];
    const int bx = blockIdx.x, tid = threadIdx.x;
    const int n = bx / BPI, kb = bx - n * BPI;
    const int lane = tid & 63, wv = tid >> 6;
    u32* hist = ws;
    u32* meta = ws + METAO;
    u32* list = ws + LISTO;

    // boundary for both groups of this image (redundant per block; hist is L2-hot)
    for (int gi = 0; gi < 2; ++gi) {
        const int g = 2 * n + gi;
        u32 loc[8];
        u32 s = 0;
        const int base = g * 2048 + tid * 8;
        #pragma unroll
        for (int j = 0; j < 8; ++j) { loc[j] = hist[base + j]; s += loc[j]; }
        // suffix-inclusive scan within wave (guarded: independent of OOB shfl semantics)
        u32 v = s;
        #pragma unroll
        for (int d = 1; d < 64; d <<= 1) {
            const u32 t = __shfl_down(v, (unsigned)d, 64);
            v += (lane + d < 64) ? t : 0u;
        }
        if (lane == 0) wsum[wv] = v;         // wave total (suffix-incl at lane 0)
        __syncthreads();
        const u32 t0 = wsum[0], t1 = wsum[1], t2 = wsum[2], t3 = wsum[3];
        const u32 tot = t0 + t1 + t2 + t3;
        u32 above = 0;                       // totals of waves after this one
        if (wv == 0) above = t1 + t2 + t3;
        else if (wv == 1) above = t2 + t3;
        else if (wv == 2) above = t3;
        v += above;                          // block-wide suffix-inclusive at tid
        if (tid == 0) s_done[gi] = (tot < NSEL) ? 1u : 0u;
        u32 run = v - s;                     // suffix over threads > tid (== old ladder)
        #pragma unroll
        for (int j = 7; j >= 0; --j) {
            const u32 Sj = run + loc[j];
            if (Sj >= NSEL && run < NSEL) {          // exactly one thread matches
                s_us[gi] = (u32)(tid * 8 + j);   // boundary 11-bit prefix
                s_R[gi] = NSEL - run;            // slots within boundary bin
            }
            run = Sj;
        }
        __syncthreads();                     // wsum reuse + s_us/s_R/s_done visibility
    }
    if (kb == 0 && tid == 0) {                   // publish for D3 (one writer/image)
        meta[2 * n] = s_us[0];     meta[8 + 2 * n] = s_R[0];     meta[16 + 2 * n] = s_done[0];
        meta[2 * n + 1] = s_us[1]; meta[8 + 2 * n + 1] = s_R[1]; meta[16 + 2 * n + 1] = s_done[1];
    }

    const int k0 = (kb * 256 + tid) * 4;
    if (k0 >= KA) return;
    const int nk = n * KA + k0;
    const u32 fw = flagsW[nk >> 2];
    if (!fw) return;                             // no members among these 4 anchors
    const float4 s4 = ((const float4*)scores)[nk >> 2];
    const float scv[4] = {s4.x, s4.y, s4.z, s4.w};
    const size_t NK = (size_t)NI * KA;
    u32* o32 = (u32*)out;
    #pragma unroll
    for (int j = 0; j < 4; ++j) {
        const u32 f = (fw >> (8 * j)) & 255u;
        if (!f) continue;
        const int gi = (f == 2u) ? 1 : 0;
        bool in = false;
        if (s_done[gi]) {
            in = true;                            // group < 256 members: take all
        } else {
            const u32 key = sortkey32(scv[j]);
            const u32 p11 = key >> 21;
            if (p11 > s_us[gi]) {
                in = true;
            } else if (p11 == s_us[gi]) {
                // boundary-bin member: defer verdict to D3 (weight stays 0)
                const int g = 2 * n + gi;
                const u32 p = atomicAdd(&meta[24 + g], 1u);
                if (p < CAPL) {
                    list[(g * CAPL + p) * 2] = key;
                    list[(g * CAPL + p) * 2 + 1] = (u32)(k0 + j);
                }
            }
        }
        if (in) {
            patch1(&o32[5 * NK + nk + j]);                 // cls_weights = 1.0
            if (f == 1u) patch1(&o32[6 * NK + nk + j]);    // reg_weights = 1.0
        }
    }
}

// ---------------- D3: boundary-bin refinement + atomic fixups (8 blocks) ----------------
__global__ void __launch_bounds__(256) kR2(const u32* __restrict__ ws,
                                           float* __restrict__ out) {
    __shared__ u32 h2[1024];
    __shared__ u32 cs[256];
    __shared__ u32 s_usb, s_R2, s_tc;
    __shared__ u32 tk[256], ti[256];
    const u32* meta = ws + METAO;
    const u32* list = ws + LISTO;
    const int g = blockIdx.x, tid = threadIdx.x;
    if (meta[16 + g]) return;                 // take-all group (uniform return)
    u32 c = meta[24 + g];
    if (c > CAPL) c = CAPL;
    const u32 R1 = meta[8 + g];
    for (u32 i = tid; i < 1024; i += 256) h2[i] = 0;
    if (tid == 0) s_tc = 0;
    __syncthreads();
    for (u32 j = tid; j < c; j += 256)
        atomicAdd(&h2[(list[(g * CAPL + j) * 2] >> 11) & 1023u], 1u);
    __syncthreads();
    // suffix scan over 1024 sub-bins
    u32 loc[4];
    u32 s = 0;
    #pragma unroll
    for (int j = 0; j < 4; ++j) { loc[j] = h2[tid * 4 + j]; s += loc[j]; }
    cs[tid] = s;
    __syncthreads();
    for (int d = 1; d < 256; d <<= 1) {
        const u32 add = (tid + d < 256) ? cs[tid + d] : 0u;
        __syncthreads();
        cs[tid] += add;
        __syncthreads();
    }
    u32 run = (tid < 255) ? cs[tid + 1] : 0u;
    #pragma unroll
    for (int j = 3; j >= 0; --j) {
        const u32 Sj = run + loc[j];
        if (Sj >= R1 && run < R1) { s_usb = (u32)(tid * 4 + j); s_R2 = R1 - run; }
        run = Sj;
    }
    __syncthreads();
    const u32 usb = s_usb, R2 = s_R2;
    const int nn = g >> 1;
    const bool posg = ((g & 1) == 0);
    const size_t NK = (size_t)NI * KA;
    u32* o32 = (u32*)out;
    for (u32 j = tid; j < c; j += 256) {
        const u32 key = list[(g * CAPL + j) * 2];
        const u32 idx = list[(g * CAPL + j) * 2 + 1];
        const u32 sb = (key >> 11) & 1023u;
        if (sb > usb) {
            const size_t o = (size_t)nn * KA + idx;
            patch1(&o32[5 * NK + o]);
            if (posg) patch1(&o32[6 * NK + o]);
        } else if (sb == usb) {
            const u32 p = atomicAdd(&s_tc, 1u);
            if (p < 256) { tk[p] = key; ti[p] = idx; }
        }
    }
    __syncthreads();
    u32 tc = s_tc;
    if (tc > 256) tc = 256;
    // rank tiny tie set by (key desc, idx asc) — stable top_k semantics
    for (u32 i = tid; i < tc; i += 256) {
        const u32 ki = tk[i], ii = ti[i];
        u32 rank = 0;
        for (u32 j = 0; j < tc; ++j) {
            const u32 kj = tk[j];
            if (kj > ki || (kj == ki && ti[j] < ii)) rank++;
        }
        if (rank < R2) {
            const size_t o = (size_t)nn * KA + ii;
            patch1(&o32[5 * NK + o]);
            if (posg) patch1(&o32[6 * NK + o]);
        }
    }
}

extern "C" void kernel_launch(void* const* d_in, const int* in_sizes, int n_in,
                              void* d_out, int out_size, void* d_ws, size_t ws_size,
                              hipStream_t stream) {
    (void)in_sizes; (void)n_in; (void)out_size; (void)ws_size;
    const float4* anchors = (const float4*)d_in[0];   // (K,4) f32
    const float*  scores  = (const float*)d_in[1];    // (N,K) f32
    const float4* gtb     = (const float4*)d_in[2];   // (N,M,4) f32
    const int*    glab    = (const int*)d_in[3];      // (N,M) int32
    float* out = (float*)d_out;

    u32* ws = (u32*)d_ws;
    u32* flags = ws + LISTO + 8 * CAPL * 2;           // u32 per 4 anchors

    AnchorTargetLayer_48052094107725_kernel<<<GRIDK, 256, 0, stream>>>(
        anchors, scores, gtb, glab, out, flags, ws);
    kP<<<GRID, 256, 0, stream>>>(scores, flags, ws, out);
    kR2<<<8, 256, 0, stream>>>(ws, out);
}